// Round 10
// baseline (874.477 us; speedup 1.0000x reference)
//
#include <hip/hip_runtime.h>
#include <hip/hip_bf16.h>
#include <math.h>

constexpr int V = 32768;
constexpr int E = 524288;
constexpr int H = 128;
constexpr int NB = 128;   // graphs per batch
constexpr int NN = 256;   // nodes per graph
constexpr int PAD = 68;   // LDS row pitch (shorts)

typedef short bf16x8 __attribute__((ext_vector_type(8)));
typedef float f32x4 __attribute__((ext_vector_type(4)));
typedef unsigned short ushort8 __attribute__((ext_vector_type(8)));
typedef unsigned short ushort4v __attribute__((ext_vector_type(4)));

static __device__ __forceinline__ float leaky(float x){ return x > 0.f ? x : 0.01f*x; }
static __device__ __forceinline__ float b2f(unsigned short u){
  unsigned int x = ((unsigned int)u) << 16; return __uint_as_float(x);
}
static __device__ __forceinline__ unsigned short f2b(float f){
  union { __hip_bfloat16 h; unsigned short u; } cv;
  cv.h = __float2bfloat16(f);
  return cv.u;
}
// split f32 into hi + lo bf16; packed low16=hi, high16=lo
static __device__ __forceinline__ unsigned int split2p(float f){
  unsigned short hh = f2b(f);
  float r = f - b2f(hh);
  unsigned short ll = f2b(r);
  return (unsigned int)hh | ((unsigned int)ll << 16);
}

// ---------------- setup kernels ----------------

__global__ void k_zero_i(int* __restrict__ p, int n){
  int i = blockIdx.x*blockDim.x + threadIdx.x;
  if (i < n) p[i] = 0;
}

__global__ void k_deg(const int* __restrict__ ei, int* __restrict__ deg){
  int e = blockIdx.x*blockDim.x + threadIdx.x;
  if (e < E) atomicAdd(&deg[ei[E+e]], 1);
}

__global__ void k_scan(const int* __restrict__ deg, int* __restrict__ offs){
  __shared__ int partial[1024];
  int t = threadIdx.x;
  int base = t*32;
  int local[32];
  int s = 0;
  #pragma unroll
  for (int i=0;i<32;i++){ local[i] = s; s += deg[base+i]; }
  partial[t] = s;
  __syncthreads();
  for (int o=1;o<1024;o<<=1){
    int v = (t>=o) ? partial[t-o] : 0;
    __syncthreads();
    partial[t] += v;
    __syncthreads();
  }
  int excl = (t==0) ? 0 : partial[t-1];
  #pragma unroll
  for (int i=0;i<32;i++) offs[base+i] = excl + local[i];
  if (t==1023) offs[V] = excl + s;
}

__global__ void k_avglog(const int* __restrict__ deg, float* __restrict__ avg_acc){
  int v = blockIdx.x*blockDim.x + threadIdx.x;
  float l = (v < V) ? logf((float)deg[v] + 1.f) : 0.f;
  __shared__ float red[256];
  int t = threadIdx.x;
  red[t] = l; __syncthreads();
  for (int s=128;s>0;s>>=1){ if (t<s) red[t]+=red[t+s]; __syncthreads(); }
  if (t==0) atomicAdd(avg_acc, red[0]);
}

__global__ void k_ampatt(const int* __restrict__ deg, const float* __restrict__ avg_acc,
                         float* __restrict__ amp, float* __restrict__ att){
  int v = blockIdx.x*blockDim.x + threadIdx.x;
  if (v >= V) return;
  float avg = avg_acc[0] * (1.f/(float)V);
  float degc = fmaxf((float)deg[v], 1.f);
  float logd = logf(degc + 1.f);
  amp[v] = logd / avg;
  att[v] = avg / logd;
}

__global__ void k_fill(const int* __restrict__ ei, const int* __restrict__ offs,
                       int* __restrict__ cursor, int* __restrict__ csr){
  int e = blockIdx.x*blockDim.x + threadIdx.x;
  if (e >= E) return;
  int d = ei[E+e];
  int slot = atomicAdd(&cursor[d], 1);
  csr[offs[d] + slot] = ei[e];
}

// ---------------- weight prep: W[K][N] f32 -> Wt_hi/Wt_lo [N][K] bf16 ----------------

__global__ void k_wt2(const float* __restrict__ W, unsigned short* __restrict__ Wh,
                      unsigned short* __restrict__ Wl, int K, int N){
  __shared__ float tile[32][33];
  int kb = blockIdx.x*32, nb = blockIdx.y*32;
  int tx = threadIdx.x, ty = threadIdx.y;   // (32,8)
  #pragma unroll
  for (int i=0;i<4;i++) tile[ty+8*i][tx] = W[(size_t)(kb+ty+8*i)*N + nb+tx];
  __syncthreads();
  #pragma unroll
  for (int i=0;i<4;i++){
    int n = ty+8*i;
    unsigned int p = split2p(tile[tx][n]);
    Wh[(size_t)(nb+n)*K + kb+tx] = (unsigned short)(p & 0xffff);
    Wl[(size_t)(nb+n)*K + kb+tx] = (unsigned short)(p >> 16);
  }
}

// ---------------- layer 1 (F=2) ----------------

__global__ void k_l1_proj(const float* __restrict__ x, const float* __restrict__ pre1_w,
                          float* __restrict__ Pd2, float* __restrict__ Ps2){
  int v = blockIdx.x*blockDim.x + threadIdx.x;
  if (v >= V) return;
  float x0 = x[v*2], x1 = x[v*2+1];
  Pd2[v*2+0] = x0*pre1_w[0] + x1*pre1_w[2];
  Pd2[v*2+1] = x0*pre1_w[1] + x1*pre1_w[3];
  Ps2[v*2+0] = x0*pre1_w[4] + x1*pre1_w[6];
  Ps2[v*2+1] = x0*pre1_w[5] + x1*pre1_w[7];
}

__global__ void k_l1_agg(const float* __restrict__ Pd2, const float* __restrict__ Ps2,
                         const float* __restrict__ pre1_b,
                         const int* __restrict__ offs, const int* __restrict__ deg,
                         const int* __restrict__ csr, float* __restrict__ agg1){
  int v = blockIdx.x*blockDim.x + threadIdx.x;
  if (v >= V) return;
  int off = offs[v], d = deg[v];
  float hb0 = Pd2[v*2]   + pre1_b[0];
  float hb1 = Pd2[v*2+1] + pre1_b[1];
  float s0=0.f,s1=0.f,q0=0.f,q1=0.f;
  float mx0=-INFINITY,mx1=-INFINITY,mn0=INFINITY,mn1=INFINITY;
  for (int i=0;i<d;i++){
    int s = csr[off+i];
    float h0 = hb0 + Ps2[s*2];
    float h1 = hb1 + Ps2[s*2+1];
    s0+=h0; s1+=h1; q0+=h0*h0; q1+=h1*h1;
    mx0=fmaxf(mx0,h0); mx1=fmaxf(mx1,h1);
    mn0=fminf(mn0,h0); mn1=fminf(mn1,h1);
  }
  float degc = fmaxf((float)d, 1.f);
  float m0 = s0/degc, m1 = s1/degc;
  float sd0 = sqrtf(fmaxf(q0/degc - m0*m0, 0.f) + 1e-5f);
  float sd1 = sqrtf(fmaxf(q1/degc - m1*m1, 0.f) + 1e-5f);
  if (d == 0){ mx0=0.f; mx1=0.f; mn0=0.f; mn1=0.f; }
  float* o = agg1 + (size_t)v*8;
  o[0]=m0; o[1]=m1; o[2]=sd0; o[3]=sd1; o[4]=mx0; o[5]=mx1; o[6]=mn0; o[7]=mn1;
}

__global__ void k_l1_in26(const float* __restrict__ x, const float* __restrict__ agg1,
                          const float* __restrict__ amp, const float* __restrict__ att,
                          float* __restrict__ in26){
  int v = blockIdx.x*blockDim.x + threadIdx.x;
  if (v >= V) return;
  float a = amp[v], t = att[v];
  float* o = in26 + (size_t)v*26;
  o[0] = x[v*2]; o[1] = x[v*2+1];
  #pragma unroll
  for (int i=0;i<8;i++){
    float g = agg1[(size_t)v*8 + i];
    o[2+i] = g; o[10+i] = g*a; o[18+i] = g*t;
  }
}

__global__ void k_gemm26(const float* __restrict__ in26, const float* __restrict__ Wp,
                         const float* __restrict__ bias, float* __restrict__ out){
  __shared__ float sin26[16][27];
  int t = threadIdx.x; // 128
  int v0 = blockIdx.x * 16;
  for (int idx = t; idx < 16*26; idx += 128){
    int r = idx / 26, c = idx % 26;
    sin26[r][c] = in26[(size_t)(v0+r)*26 + c];
  }
  __syncthreads();
  float acc[16];
  #pragma unroll
  for (int r=0;r<16;r++) acc[r] = 0.f;
  for (int k=0;k<26;k++){
    float wv = Wp[k*128 + t];
    #pragma unroll
    for (int r=0;r<16;r++) acc[r] = fmaf(sin26[r][k], wv, acc[r]);
  }
  float bb = bias[t];
  for (int r=0;r<16;r++) out[(size_t)(v0+r)*128 + t] = acc[r] + bb;
}

// ======== 32-row full-N split-precision MFMA GEMM, B from global(L2) ========
// grid V/32 (1024 blocks = 4/CU); 4 waves, wave w -> cols w*32. acc += Ah*Wh + Al*Wh + Ah*Wl.

template<int OUT_MODE> // 0 = f32, 2 = f32 + leaky
__global__ __launch_bounds__(256) void k_lin32(const float* __restrict__ A,
    const unsigned short* __restrict__ Wh, const unsigned short* __restrict__ Wl,
    const float* __restrict__ bias, float* __restrict__ out){
  __shared__ unsigned short sAh[32*PAD];
  __shared__ unsigned short sAl[32*PAD];
  int t = threadIdx.x;
  int v0 = blockIdx.x * 32;
  int lane = t & 63, w = t >> 6;
  int lr = lane & 15, lk = lane >> 4;
  int bbase[2];
  #pragma unroll
  for (int n=0;n<2;n++) bbase[n] = (w*32 + n*16 + lr)*128 + lk*8;
  f32x4 acc[2][2];
  #pragma unroll
  for (int m=0;m<2;m++)
    #pragma unroll
    for (int n=0;n<2;n++) acc[m][n] = (f32x4)(0.f);

  for (int kb = 0; kb < 128; kb += 64){
    #pragma unroll
    for (int i=0;i<2;i++){
      int u = t + i*256, row = u >> 4, slot = u & 15;
      float4 va = *(const float4*)(A + (size_t)(v0+row)*128 + kb + slot*4);
      unsigned int p0 = split2p(va.x), p1 = split2p(va.y);
      unsigned int p2 = split2p(va.z), p3 = split2p(va.w);
      ushort4v hi, lo;
      hi[0]=(unsigned short)p0; lo[0]=(unsigned short)(p0>>16);
      hi[1]=(unsigned short)p1; lo[1]=(unsigned short)(p1>>16);
      hi[2]=(unsigned short)p2; lo[2]=(unsigned short)(p2>>16);
      hi[3]=(unsigned short)p3; lo[3]=(unsigned short)(p3>>16);
      *(ushort4v*)&sAh[row*PAD + slot*4] = hi;
      *(ushort4v*)&sAl[row*PAD + slot*4] = lo;
    }
    __syncthreads();
    #pragma unroll
    for (int kk=0; kk<64; kk+=32){
      bf16x8 ah[2], al[2], bh[2], bl[2];
      #pragma unroll
      for (int m=0;m<2;m++){
        ah[m] = *(const bf16x8*)&sAh[(m*16 + lr)*PAD + kk + lk*8];
        al[m] = *(const bf16x8*)&sAl[(m*16 + lr)*PAD + kk + lk*8];
      }
      #pragma unroll
      for (int n=0;n<2;n++){
        bh[n] = *(const bf16x8*)(Wh + bbase[n] + kb + kk);
        bl[n] = *(const bf16x8*)(Wl + bbase[n] + kb + kk);
      }
      #pragma unroll
      for (int m=0;m<2;m++)
        #pragma unroll
        for (int n=0;n<2;n++){
          acc[m][n] = __builtin_amdgcn_mfma_f32_16x16x32_bf16(ah[m], bh[n], acc[m][n], 0, 0, 0);
          acc[m][n] = __builtin_amdgcn_mfma_f32_16x16x32_bf16(al[m], bh[n], acc[m][n], 0, 0, 0);
          acc[m][n] = __builtin_amdgcn_mfma_f32_16x16x32_bf16(ah[m], bl[n], acc[m][n], 0, 0, 0);
        }
    }
    __syncthreads();
  }

  #pragma unroll
  for (int m=0;m<2;m++){
    #pragma unroll
    for (int n=0;n<2;n++){
      int col = w*32 + n*16 + lr;
      float bb = bias ? bias[col] : 0.f;
      #pragma unroll
      for (int r=0;r<4;r++){
        int row = v0 + m*16 + lk*4 + r;
        float val = acc[m][n][r] + bb;
        if (OUT_MODE == 2) val = leaky(val);
        out[(size_t)row*128 + col] = val;
      }
    }
  }
}

// ======== fused pre GEMM: Pd = A@Wd, Ps = A@Ws; Wt combined [128][256] hi/lo ========

__global__ __launch_bounds__(256) void k_pre64(const float* __restrict__ A,
    const unsigned short* __restrict__ Wh, const unsigned short* __restrict__ Wl,
    float* __restrict__ Pd, float* __restrict__ Ps){
  __shared__ unsigned short sAh[64*PAD];
  __shared__ unsigned short sAl[64*PAD];
  int t = threadIdx.x;
  int bid = blockIdx.x;
  int rowt = bid >> 1, colt = bid & 1;
  int v0 = rowt * 64;
  int lane = t & 63, w = t >> 6;
  int wm = w & 1, wn = w >> 1;
  int lr = lane & 15, lk = lane >> 4;
  int brow0 = (colt*64 + wn*32 + lr)*256 + lk*8;
  int brow1 = brow0 + 16*256;
  f32x4 accd[2][2], accs[2][2];
  #pragma unroll
  for (int m=0;m<2;m++)
    #pragma unroll
    for (int n=0;n<2;n++){ accd[m][n] = (f32x4)(0.f); accs[m][n] = (f32x4)(0.f); }

  for (int kb = 0; kb < 128; kb += 64){
    #pragma unroll
    for (int i=0;i<4;i++){
      int u = t + i*256, row = u >> 4, slot = u & 15;
      float4 va = *(const float4*)(A + (size_t)(v0+row)*128 + kb + slot*4);
      unsigned int p0 = split2p(va.x), p1 = split2p(va.y);
      unsigned int p2 = split2p(va.z), p3 = split2p(va.w);
      ushort4v hi, lo;
      hi[0]=(unsigned short)p0; lo[0]=(unsigned short)(p0>>16);
      hi[1]=(unsigned short)p1; lo[1]=(unsigned short)(p1>>16);
      hi[2]=(unsigned short)p2; lo[2]=(unsigned short)(p2>>16);
      hi[3]=(unsigned short)p3; lo[3]=(unsigned short)(p3>>16);
      *(ushort4v*)&sAh[row*PAD + slot*4] = hi;
      *(ushort4v*)&sAl[row*PAD + slot*4] = lo;
    }
    __syncthreads();
    #pragma unroll
    for (int kk=0; kk<64; kk+=32){
      bf16x8 ah[2], al[2], bh[2], bl[2];
      #pragma unroll
      for (int m=0;m<2;m++){
        ah[m] = *(const bf16x8*)&sAh[(wm*32 + m*16 + lr)*PAD + kk + lk*8];
        al[m] = *(const bf16x8*)&sAl[(wm*32 + m*16 + lr)*PAD + kk + lk*8];
      }
      bh[0] = *(const bf16x8*)(Wh + brow0 + kb + kk);
      bh[1] = *(const bf16x8*)(Wh + brow1 + kb + kk);
      bl[0] = *(const bf16x8*)(Wl + brow0 + kb + kk);
      bl[1] = *(const bf16x8*)(Wl + brow1 + kb + kk);
      #pragma unroll
      for (int m=0;m<2;m++)
        #pragma unroll
        for (int n=0;n<2;n++){
          accd[m][n] = __builtin_amdgcn_mfma_f32_16x16x32_bf16(ah[m], bh[n], accd[m][n], 0, 0, 0);
          accd[m][n] = __builtin_amdgcn_mfma_f32_16x16x32_bf16(al[m], bh[n], accd[m][n], 0, 0, 0);
          accd[m][n] = __builtin_amdgcn_mfma_f32_16x16x32_bf16(ah[m], bl[n], accd[m][n], 0, 0, 0);
        }
      bh[0] = *(const bf16x8*)(Wh + brow0 + 128 + kb + kk);
      bh[1] = *(const bf16x8*)(Wh + brow1 + 128 + kb + kk);
      bl[0] = *(const bf16x8*)(Wl + brow0 + 128 + kb + kk);
      bl[1] = *(const bf16x8*)(Wl + brow1 + 128 + kb + kk);
      #pragma unroll
      for (int m=0;m<2;m++)
        #pragma unroll
        for (int n=0;n<2;n++){
          accs[m][n] = __builtin_amdgcn_mfma_f32_16x16x32_bf16(ah[m], bh[n], accs[m][n], 0, 0, 0);
          accs[m][n] = __builtin_amdgcn_mfma_f32_16x16x32_bf16(al[m], bh[n], accs[m][n], 0, 0, 0);
          accs[m][n] = __builtin_amdgcn_mfma_f32_16x16x32_bf16(ah[m], bl[n], accs[m][n], 0, 0, 0);
        }
    }
    __syncthreads();
  }

  #pragma unroll
  for (int m=0;m<2;m++){
    #pragma unroll
    for (int n=0;n<2;n++){
      int col = colt*64 + wn*32 + n*16 + lr;
      #pragma unroll
      for (int r=0;r<4;r++){
        int row = v0 + wm*32 + m*16 + lk*4 + r;
        Pd[(size_t)row*128 + col] = accd[m][n][r];
        Ps[(size_t)row*128 + col] = accs[m][n][r];
      }
    }
  }
}

// ---------------- aggregation (H=128), f32 out, 2 nodes/block, unroll-4 ----------------

__global__ __launch_bounds__(256) void k_agg(const float* __restrict__ Pd, const float* __restrict__ Ps,
                      const float* __restrict__ pre_b, const int* __restrict__ offs,
                      const int* __restrict__ deg, const int* __restrict__ csr,
                      float* __restrict__ aggf){
  int t = threadIdx.x;
  int v = blockIdx.x*2 + (t >> 7);
  int f = t & 127;
  int off = offs[v], d = deg[v];
  float hb = Pd[(size_t)v*128 + f] + pre_b[f];
  float s=0.f, q=0.f, mx=-INFINITY, mn=INFINITY;
  int i = 0;
  for (; i+4 <= d; i += 4){
    int i0 = csr[off+i], i1 = csr[off+i+1], i2 = csr[off+i+2], i3 = csr[off+i+3];
    float h0 = hb + Ps[(size_t)i0*128 + f];
    float h1 = hb + Ps[(size_t)i1*128 + f];
    float h2 = hb + Ps[(size_t)i2*128 + f];
    float h3 = hb + Ps[(size_t)i3*128 + f];
    s += (h0+h1) + (h2+h3);
    q = fmaf(h0,h0, fmaf(h1,h1, fmaf(h2,h2, fmaf(h3,h3, q))));
    mx = fmaxf(fmaxf(fmaxf(mx,h0),fmaxf(h1,h2)),h3);
    mn = fminf(fminf(fminf(mn,h0),fminf(h1,h2)),h3);
  }
  for (; i < d; i++){
    int sv = csr[off+i];
    float h = hb + Ps[(size_t)sv*128 + f];
    s += h; q = fmaf(h,h,q);
    mx = fmaxf(mx, h); mn = fminf(mn, h);
  }
  float degc = fmaxf((float)d, 1.f);
  float mean = s/degc;
  float stdv = sqrtf(fmaxf(q/degc - mean*mean, 0.f) + 1e-5f);
  if (d == 0){ mx = 0.f; mn = 0.f; }
  size_t o = (size_t)v*512;
  aggf[o+f]      = mean;
  aggf[o+128+f]  = stdv;
  aggf[o+256+f]  = mx;
  aggf[o+384+f]  = mn;
}

// ======== post GEMM (scaling commuted to epilogue): A read ONCE, 32-row tiles ========
// out = state@W0 + agg@W1 + amp*(agg@W2) + att*(agg@W3)
// grid V/32 (1024 blocks = 4/CU); 4 waves, wave w covers cols w*32.
// Wt regions in [128][1664]: W0 @ k=0, W1 @ 128, W2 @ 640, W3 @ 1152.

__global__ __launch_bounds__(256) void k_postY(const float* __restrict__ state,
    const float* __restrict__ aggf, const float* __restrict__ amp, const float* __restrict__ att,
    const unsigned short* __restrict__ Wh, const unsigned short* __restrict__ Wl,
    const float* __restrict__ bias, float* __restrict__ out){
  __shared__ unsigned short sAh[32*PAD];
  __shared__ unsigned short sAl[32*PAD];
  __shared__ float sScl[2][32];
  int t = threadIdx.x;
  int v0 = blockIdx.x * 32;
  if (t < 32) sScl[0][t] = amp[v0+t];
  else if (t < 64) sScl[1][t-32] = att[v0+t-32];
  int lane = t & 63, w = t >> 6;     // wave w: cols w*32 .. w*32+31
  int lr = lane & 15, lk = lane >> 4;
  int bb[2];
  #pragma unroll
  for (int n=0;n<2;n++) bb[n] = (w*32 + n*16 + lr)*1664 + lk*8;
  f32x4 a1[2][2], a2[2][2], a3[2][2];
  #pragma unroll
  for (int m=0;m<2;m++)
    #pragma unroll
    for (int n=0;n<2;n++){ a1[m][n]=(f32x4)(0.f); a2[m][n]=(f32x4)(0.f); a3[m][n]=(f32x4)(0.f); }

  // ---- state part: K = 128, W0 region ----
  for (int kb = 0; kb < 128; kb += 64){
    #pragma unroll
    for (int i=0;i<2;i++){
      int u = t + i*256, row = u >> 4, slot = u & 15;
      float4 va = *(const float4*)(state + (size_t)(v0+row)*128 + kb + slot*4);
      unsigned int p0 = split2p(va.x), p1 = split2p(va.y);
      unsigned int p2 = split2p(va.z), p3 = split2p(va.w);
      ushort4v hi, lo;
      hi[0]=(unsigned short)p0; lo[0]=(unsigned short)(p0>>16);
      hi[1]=(unsigned short)p1; lo[1]=(unsigned short)(p1>>16);
      hi[2]=(unsigned short)p2; lo[2]=(unsigned short)(p2>>16);
      hi[3]=(unsigned short)p3; lo[3]=(unsigned short)(p3>>16);
      *(ushort4v*)&sAh[row*PAD + slot*4] = hi;
      *(ushort4v*)&sAl[row*PAD + slot*4] = lo;
    }
    __syncthreads();
    #pragma unroll
    for (int kk=0; kk<64; kk+=32){
      bf16x8 ah[2], al[2], bh[2], bl[2];
      #pragma unroll
      for (int m=0;m<2;m++){
        ah[m] = *(const bf16x8*)&sAh[(m*16 + lr)*PAD + kk + lk*8];
        al[m] = *(const bf16x8*)&sAl[(m*16 + lr)*PAD + kk + lk*8];
      }
      #pragma unroll
      for (int n=0;n<2;n++){
        bh[n] = *(const bf16x8*)(Wh + bb[n] + kb + kk);
        bl[n] = *(const bf16x8*)(Wl + bb[n] + kb + kk);
      }
      #pragma unroll
      for (int m=0;m<2;m++)
        #pragma unroll
        for (int n=0;n<2;n++){
          a1[m][n] = __builtin_amdgcn_mfma_f32_16x16x32_bf16(ah[m], bh[n], a1[m][n], 0, 0, 0);
          a1[m][n] = __builtin_amdgcn_mfma_f32_16x16x32_bf16(al[m], bh[n], a1[m][n], 0, 0, 0);
          a1[m][n] = __builtin_amdgcn_mfma_f32_16x16x32_bf16(ah[m], bl[n], a1[m][n], 0, 0, 0);
        }
    }
    __syncthreads();
  }

  // ---- agg part: K = 512, W1/W2/W3 regions on the SAME staged A ----
  for (int kb = 0; kb < 512; kb += 64){
    #pragma unroll
    for (int i=0;i<2;i++){
      int u = t + i*256, row = u >> 4, slot = u & 15;
      float4 va = *(const float4*)(aggf + (size_t)(v0+row)*512 + kb + slot*4);
      unsigned int p0 = split2p(va.x), p1 = split2p(va.y);
      unsigned int p2 = split2p(va.z), p3 = split2p(va.w);
      ushort4v hi, lo;
      hi[0]=(unsigned short)p0; lo[0]=(unsigned short)(p0>>16);
      hi[1]=(unsigned short)p1; lo[1]=(unsigned short)(p1>>16);
      hi[2]=(unsigned short)p2; lo[2]=(unsigned short)(p2>>16);
      hi[3]=(unsigned short)p3; lo[3]=(unsigned short)(p3>>16);
      *(ushort4v*)&sAh[row*PAD + slot*4] = hi;
      *(ushort4v*)&sAl[row*PAD + slot*4] = lo;
    }
    __syncthreads();
    #pragma unroll
    for (int kk=0; kk<64; kk+=32){
      bf16x8 ah[2], al[2];
      #pragma unroll
      for (int m=0;m<2;m++){
        ah[m] = *(const bf16x8*)&sAh[(m*16 + lr)*PAD + kk + lk*8];
        al[m] = *(const bf16x8*)&sAl[(m*16 + lr)*PAD + kk + lk*8];
      }
      #pragma unroll
      for (int j=0;j<3;j++){
        int off = 128 + j*512 + kb + kk;
        bf16x8 bh[2], bl[2];
        #pragma unroll
        for (int n=0;n<2;n++){
          bh[n] = *(const bf16x8*)(Wh + bb[n] + off);
          bl[n] = *(const bf16x8*)(Wl + bb[n] + off);
        }
        #pragma unroll
        for (int m=0;m<2;m++)
          #pragma unroll
          for (int n=0;n<2;n++){
            f32x4 acc = (j==0) ? a1[m][n] : (j==1) ? a2[m][n] : a3[m][n];
            acc = __builtin_amdgcn_mfma_f32_16x16x32_bf16(ah[m], bh[n], acc, 0, 0, 0);
            acc = __builtin_amdgcn_mfma_f32_16x16x32_bf16(al[m], bh[n], acc, 0, 0, 0);
            acc = __builtin_amdgcn_mfma_f32_16x16x32_bf16(ah[m], bl[n], acc, 0, 0, 0);
            if (j==0) a1[m][n] = acc; else if (j==1) a2[m][n] = acc; else a3[m][n] = acc;
          }
      }
    }
    __syncthreads();
  }

  // ---- epilogue: out = a1 + bias + amp*a2 + att*a3 ----
  #pragma unroll
  for (int m=0;m<2;m++){
    #pragma unroll
    for (int n=0;n<2;n++){
      int col = w*32 + n*16 + lr;
      float bbv = bias[col];
      #pragma unroll
      for (int r=0;r<4;r++){
        int rl = m*16 + lk*4 + r;
        float val = a1[m][n][r] + bbv + sScl[0][rl]*a2[m][n][r] + sScl[1][rl]*a3[m][n][r];
        out[(size_t)(v0+rl)*128 + col] = val;
      }
    }
  }
}

// ---------------- readout tail ----------------

__global__ void k_tail(const float* __restrict__ h1, const float* __restrict__ r2_w,
                       const float* __restrict__ r2_b, const float* __restrict__ r3_w,
                       const float* __restrict__ r3_b, const float* __restrict__ target_n,
                       float* __restrict__ out, float* __restrict__ gacc){
  __shared__ float sh[16][129];
  __shared__ float h2[16][8];
  __shared__ float red[128];
  int t = threadIdx.x; // 128
  int v0 = blockIdx.x * 16;
  for (int r=0;r<16;r++) sh[r][t] = h1[(size_t)(v0+r)*128 + t];
  __syncthreads();
  int n = t >> 3, o = t & 7;
  float acc = r2_b[o];
  for (int k=0;k<128;k++) acc = fmaf(sh[n][k], r2_w[k*8+o], acc);
  h2[n][o] = leaky(acc);
  __syncthreads();
  float err = 0.f;
  if (t < 48){
    int n3 = t / 3, o3 = t % 3;
    float a = r3_b[o3];
    #pragma unroll
    for (int k=0;k<8;k++) a = fmaf(h2[n3][k], r3_w[k*3+o3], a);
    a = leaky(a);
    int v = v0 + n3;
    out[(size_t)v*3 + o3] = a;
    float d = a - target_n[(size_t)v*3 + o3];
    err = d*d;
  }
  red[t] = err; __syncthreads();
  for (int s=64;s>0;s>>=1){ if (t<s) red[t]+=red[t+s]; __syncthreads(); }
  if (t==0) atomicAdd(&gacc[v0 / NN], red[0]);
}

__global__ void k_finalize(const float* __restrict__ gacc, float* __restrict__ out){
  __shared__ float red[128];
  int t = threadIdx.x; // 128
  float a = gacc[t];
  out[(size_t)V*3 + 1 + t] = a / (float)(NN*3);
  red[t] = a; __syncthreads();
  for (int s=64;s>0;s>>=1){ if (t<s) red[t]+=red[t+s]; __syncthreads(); }
  if (t==0) out[(size_t)V*3] = red[0] / (float)(V*3);
}

// ---------------- launch ----------------

extern "C" void kernel_launch(void* const* d_in, const int* in_sizes, int n_in,
                              void* d_out, int out_size, void* d_ws, size_t ws_size,
                              hipStream_t stream){
  const float* x        = (const float*)d_in[0];
  const int*   ei       = (const int*)d_in[1];
  const float* target_n = (const float*)d_in[2];
  const float* pre1_w = (const float*)d_in[4];
  const float* pre1_b = (const float*)d_in[5];
  const float* post1_w= (const float*)d_in[6];
  const float* post1_b= (const float*)d_in[7];
  const float* lin1_w = (const float*)d_in[8];
  const float* lin1_b = (const float*)d_in[9];
  const float* pre_w  = (const float*)d_in[10];
  const float* pre_b  = (const float*)d_in[11];
  const float* post_w = (const float*)d_in[12];
  const float* post_b = (const float*)d_in[13];
  const float* lin_w  = (const float*)d_in[14];
  const float* lin_b  = (const float*)d_in[15];
  const float* r1_w = (const float*)d_in[16];
  const float* r1_b = (const float*)d_in[17];
  const float* r2_w = (const float*)d_in[18];
  const float* r2_b = (const float*)d_in[19];
  const float* r3_w = (const float*)d_in[20];
  const float* r3_b = (const float*)d_in[21];
  float* out = (float*)d_out;

  char* wp = (char*)d_ws;
  auto alloc = [&](size_t bytes){ void* p = (void*)wp; wp += (bytes + 255) & ~(size_t)255; return p; };
  // zero region must stay contiguous: deg, cursor, avg_acc, gacc
  int*   deg     = (int*)  alloc((size_t)V*4);
  int*   cursor  = (int*)  alloc((size_t)V*4);
  float* avg_acc = (float*)alloc(4);
  float* gacc    = (float*)alloc((size_t)NB*4);
  int*   offs    = (int*)  alloc((size_t)(V+1)*4);
  int*   csr     = (int*)  alloc((size_t)E*4);
  float* amp     = (float*)alloc((size_t)V*4);
  float* att     = (float*)alloc((size_t)V*4);
  float* Pd      = (float*)alloc((size_t)V*H*4);
  float* Ps      = (float*)alloc((size_t)V*H*4);
  float* aggf    = (float*)alloc((size_t)V*512*4);     // 64 MB; layer-1 scratch aliases in here
  float* tmpf    = (float*)alloc((size_t)V*H*4);
  float* stA     = (float*)alloc((size_t)V*H*4);
  float* stB     = (float*)alloc((size_t)V*H*4);
  unsigned short* wt_pre_h   = (unsigned short*)alloc((size_t)H*2*H*2);  // [128][256]
  unsigned short* wt_pre_l   = (unsigned short*)alloc((size_t)H*2*H*2);
  unsigned short* wt_lin_h   = (unsigned short*)alloc((size_t)H*H*2);
  unsigned short* wt_lin_l   = (unsigned short*)alloc((size_t)H*H*2);
  unsigned short* wt_lin1_h  = (unsigned short*)alloc((size_t)H*H*2);
  unsigned short* wt_lin1_l  = (unsigned short*)alloc((size_t)H*H*2);
  unsigned short* wt_r1_h    = (unsigned short*)alloc((size_t)H*H*2);
  unsigned short* wt_r1_l    = (unsigned short*)alloc((size_t)H*H*2);
  unsigned short* wt_post_h  = (unsigned short*)alloc((size_t)13*H*H*2);
  unsigned short* wt_post_l  = (unsigned short*)alloc((size_t)13*H*H*2);

  // layer-1 scratch aliased into aggf (used strictly before first k_agg)
  float* agg1 = aggf;                                  // V*8 f32 = 1 MB
  float* in26 = aggf + (size_t)V*8;                    // V*26 f32 = 3.4 MB

  int zeroN = (int)(((char*)offs - (char*)deg) / 4);
  k_zero_i<<<(zeroN+255)/256, 256, 0, stream>>>(deg, zeroN);
  k_deg<<<E/256, 256, 0, stream>>>(ei, deg);
  k_scan<<<1, 1024, 0, stream>>>(deg, offs);
  k_avglog<<<V/256, 256, 0, stream>>>(deg, avg_acc);
  k_ampatt<<<V/256, 256, 0, stream>>>(deg, avg_acc, amp, att);
  k_fill<<<E/256, 256, 0, stream>>>(ei, offs, cursor, csr);

  // weight prep (bf16 hi/lo, transposed)
  {
    dim3 b(32,8);
    k_wt2<<<dim3(8,4),  b, 0, stream>>>(pre_w,   wt_pre_h,  wt_pre_l, 256, 128);  // [256,128] -> [128][256]
    k_wt2<<<dim3(52,4), b, 0, stream>>>(post_w,  wt_post_h, wt_post_l, 1664, 128);
    k_wt2<<<dim3(4,4),  b, 0, stream>>>(lin_w,   wt_lin_h,  wt_lin_l,  128, 128);
    k_wt2<<<dim3(4,4),  b, 0, stream>>>(lin1_w,  wt_lin1_h, wt_lin1_l, 128, 128);
    k_wt2<<<dim3(4,4),  b, 0, stream>>>(r1_w,    wt_r1_h,   wt_r1_l,   128, 128);
  }

  // layer 1 (F=2) — all f32
  k_l1_proj<<<V/256, 256, 0, stream>>>(x, pre1_w, Pd, Ps);
  k_l1_agg<<<V/256, 256, 0, stream>>>(Pd, Ps, pre1_b, offs, deg, csr, agg1);
  k_l1_in26<<<V/256, 256, 0, stream>>>(x, agg1, amp, att, in26);
  k_gemm26<<<V/16, 128, 0, stream>>>(in26, post1_w, post1_b, tmpf);
  k_lin32<0><<<V/32, 256, 0, stream>>>(tmpf, wt_lin1_h, wt_lin1_l, lin1_b, stA);

  // 3 propagation layers (H=128)
  float* cur = stA;
  float* nxt = stB;
  for (int l=0; l<3; l++){
    k_pre64<<<(V/64)*2, 256, 0, stream>>>(cur, wt_pre_h, wt_pre_l, Pd, Ps);
    k_agg<<<V/2, 256, 0, stream>>>(Pd, Ps, pre_b, offs, deg, csr, aggf);
    k_postY<<<V/32, 256, 0, stream>>>(cur, aggf, amp, att, wt_post_h, wt_post_l, post_b, tmpf);
    k_lin32<0><<<V/32, 256, 0, stream>>>(tmpf, wt_lin_h, wt_lin_l, lin_b, nxt);
    float* t2 = cur; cur = nxt; nxt = t2;
  }

  // readout
  k_lin32<2><<<V/32, 256, 0, stream>>>(cur, wt_r1_h, wt_r1_l, r1_b, tmpf);
  k_tail<<<V/16, 128, 0, stream>>>(tmpf, r2_w, r2_b, r3_w, r3_b, target_n, out, gacc);
  k_finalize<<<1, 128, 0, stream>>>(gacc, out);
}

// Round 11
// 684.749 us; speedup vs baseline: 1.2771x; 1.2771x over previous
//
#include <hip/hip_runtime.h>
#include <hip/hip_bf16.h>
#include <math.h>

constexpr int V = 32768;
constexpr int E = 524288;
constexpr int H = 128;
constexpr int NB = 128;   // graphs per batch
constexpr int NN = 256;   // nodes per graph
constexpr int PAD = 68;   // LDS row pitch (shorts)

typedef short bf16x8 __attribute__((ext_vector_type(8)));
typedef float f32x4 __attribute__((ext_vector_type(4)));
typedef unsigned short ushort8 __attribute__((ext_vector_type(8)));
typedef unsigned short ushort4v __attribute__((ext_vector_type(4)));

static __device__ __forceinline__ float leaky(float x){ return x > 0.f ? x : 0.01f*x; }
static __device__ __forceinline__ float b2f(unsigned short u){
  unsigned int x = ((unsigned int)u) << 16; return __uint_as_float(x);
}
static __device__ __forceinline__ unsigned short f2b(float f){
  union { __hip_bfloat16 h; unsigned short u; } cv;
  cv.h = __float2bfloat16(f);
  return cv.u;
}
// split f32 into hi + lo bf16; packed low16=hi, high16=lo
static __device__ __forceinline__ unsigned int split2p(float f){
  unsigned short hh = f2b(f);
  float r = f - b2f(hh);
  unsigned short ll = f2b(r);
  return (unsigned int)hh | ((unsigned int)ll << 16);
}

// ---------------- setup kernels ----------------

__global__ void k_zero_i(int* __restrict__ p, int n){
  int i = blockIdx.x*blockDim.x + threadIdx.x;
  if (i < n) p[i] = 0;
}

__global__ void k_deg(const int* __restrict__ ei, int* __restrict__ deg){
  int e = blockIdx.x*blockDim.x + threadIdx.x;
  if (e < E) atomicAdd(&deg[ei[E+e]], 1);
}

__global__ void k_scan(const int* __restrict__ deg, int* __restrict__ offs){
  __shared__ int partial[1024];
  int t = threadIdx.x;
  int base = t*32;
  int local[32];
  int s = 0;
  #pragma unroll
  for (int i=0;i<32;i++){ local[i] = s; s += deg[base+i]; }
  partial[t] = s;
  __syncthreads();
  for (int o=1;o<1024;o<<=1){
    int v = (t>=o) ? partial[t-o] : 0;
    __syncthreads();
    partial[t] += v;
    __syncthreads();
  }
  int excl = (t==0) ? 0 : partial[t-1];
  #pragma unroll
  for (int i=0;i<32;i++) offs[base+i] = excl + local[i];
  if (t==1023) offs[V] = excl + s;
}

__global__ void k_avglog(const int* __restrict__ deg, float* __restrict__ avg_acc){
  int v = blockIdx.x*blockDim.x + threadIdx.x;
  float l = (v < V) ? logf((float)deg[v] + 1.f) : 0.f;
  __shared__ float red[256];
  int t = threadIdx.x;
  red[t] = l; __syncthreads();
  for (int s=128;s>0;s>>=1){ if (t<s) red[t]+=red[t+s]; __syncthreads(); }
  if (t==0) atomicAdd(avg_acc, red[0]);
}

__global__ void k_ampatt(const int* __restrict__ deg, const float* __restrict__ avg_acc,
                         float* __restrict__ amp, float* __restrict__ att){
  int v = blockIdx.x*blockDim.x + threadIdx.x;
  if (v >= V) return;
  float avg = avg_acc[0] * (1.f/(float)V);
  float degc = fmaxf((float)deg[v], 1.f);
  float logd = logf(degc + 1.f);
  amp[v] = logd / avg;
  att[v] = avg / logd;
}

__global__ void k_fill(const int* __restrict__ ei, const int* __restrict__ offs,
                       int* __restrict__ cursor, int* __restrict__ csr){
  int e = blockIdx.x*blockDim.x + threadIdx.x;
  if (e >= E) return;
  int d = ei[E+e];
  int slot = atomicAdd(&cursor[d], 1);
  csr[offs[d] + slot] = ei[e];
}

// ---------------- weight prep: W[K][N] f32 -> Wt_hi/Wt_lo [N][K] bf16 ----------------

__global__ void k_wt2(const float* __restrict__ W, unsigned short* __restrict__ Wh,
                      unsigned short* __restrict__ Wl, int K, int N){
  __shared__ float tile[32][33];
  int kb = blockIdx.x*32, nb = blockIdx.y*32;
  int tx = threadIdx.x, ty = threadIdx.y;   // (32,8)
  #pragma unroll
  for (int i=0;i<4;i++) tile[ty+8*i][tx] = W[(size_t)(kb+ty+8*i)*N + nb+tx];
  __syncthreads();
  #pragma unroll
  for (int i=0;i<4;i++){
    int n = ty+8*i;
    unsigned int p = split2p(tile[tx][n]);
    Wh[(size_t)(nb+n)*K + kb+tx] = (unsigned short)(p & 0xffff);
    Wl[(size_t)(nb+n)*K + kb+tx] = (unsigned short)(p >> 16);
  }
}

// ---------------- layer 1 (F=2) ----------------

__global__ void k_l1_proj(const float* __restrict__ x, const float* __restrict__ pre1_w,
                          float* __restrict__ Pd2, float* __restrict__ Ps2){
  int v = blockIdx.x*blockDim.x + threadIdx.x;
  if (v >= V) return;
  float x0 = x[v*2], x1 = x[v*2+1];
  Pd2[v*2+0] = x0*pre1_w[0] + x1*pre1_w[2];
  Pd2[v*2+1] = x0*pre1_w[1] + x1*pre1_w[3];
  Ps2[v*2+0] = x0*pre1_w[4] + x1*pre1_w[6];
  Ps2[v*2+1] = x0*pre1_w[5] + x1*pre1_w[7];
}

__global__ void k_l1_agg(const float* __restrict__ Pd2, const float* __restrict__ Ps2,
                         const float* __restrict__ pre1_b,
                         const int* __restrict__ offs, const int* __restrict__ deg,
                         const int* __restrict__ csr, float* __restrict__ agg1){
  int v = blockIdx.x*blockDim.x + threadIdx.x;
  if (v >= V) return;
  int off = offs[v], d = deg[v];
  float hb0 = Pd2[v*2]   + pre1_b[0];
  float hb1 = Pd2[v*2+1] + pre1_b[1];
  float s0=0.f,s1=0.f,q0=0.f,q1=0.f;
  float mx0=-INFINITY,mx1=-INFINITY,mn0=INFINITY,mn1=INFINITY;
  for (int i=0;i<d;i++){
    int s = csr[off+i];
    float h0 = hb0 + Ps2[s*2];
    float h1 = hb1 + Ps2[s*2+1];
    s0+=h0; s1+=h1; q0+=h0*h0; q1+=h1*h1;
    mx0=fmaxf(mx0,h0); mx1=fmaxf(mx1,h1);
    mn0=fminf(mn0,h0); mn1=fminf(mn1,h1);
  }
  float degc = fmaxf((float)d, 1.f);
  float m0 = s0/degc, m1 = s1/degc;
  float sd0 = sqrtf(fmaxf(q0/degc - m0*m0, 0.f) + 1e-5f);
  float sd1 = sqrtf(fmaxf(q1/degc - m1*m1, 0.f) + 1e-5f);
  if (d == 0){ mx0=0.f; mx1=0.f; mn0=0.f; mn1=0.f; }
  float* o = agg1 + (size_t)v*8;
  o[0]=m0; o[1]=m1; o[2]=sd0; o[3]=sd1; o[4]=mx0; o[5]=mx1; o[6]=mn0; o[7]=mn1;
}

__global__ void k_l1_in26(const float* __restrict__ x, const float* __restrict__ agg1,
                          const float* __restrict__ amp, const float* __restrict__ att,
                          float* __restrict__ in26){
  int v = blockIdx.x*blockDim.x + threadIdx.x;
  if (v >= V) return;
  float a = amp[v], t = att[v];
  float* o = in26 + (size_t)v*26;
  o[0] = x[v*2]; o[1] = x[v*2+1];
  #pragma unroll
  for (int i=0;i<8;i++){
    float g = agg1[(size_t)v*8 + i];
    o[2+i] = g; o[10+i] = g*a; o[18+i] = g*t;
  }
}

__global__ void k_gemm26(const float* __restrict__ in26, const float* __restrict__ Wp,
                         const float* __restrict__ bias, float* __restrict__ out){
  __shared__ float sin26[16][27];
  int t = threadIdx.x; // 128
  int v0 = blockIdx.x * 16;
  for (int idx = t; idx < 16*26; idx += 128){
    int r = idx / 26, c = idx % 26;
    sin26[r][c] = in26[(size_t)(v0+r)*26 + c];
  }
  __syncthreads();
  float acc[16];
  #pragma unroll
  for (int r=0;r<16;r++) acc[r] = 0.f;
  for (int k=0;k<26;k++){
    float wv = Wp[k*128 + t];
    #pragma unroll
    for (int r=0;r<16;r++) acc[r] = fmaf(sin26[r][k], wv, acc[r]);
  }
  float bb = bias[t];
  for (int r=0;r<16;r++) out[(size_t)(v0+r)*128 + t] = acc[r] + bb;
}

// ======== full-N 64x128 split-precision MFMA GEMM (A read once), B from global(L2) ========
// grid V/64; 4 waves 2x2, each 32x64. acc += Ah*Wh + Al*Wh + Ah*Wl.

template<int OUT_MODE> // 0 = f32, 2 = f32 + leaky
__global__ __launch_bounds__(256) void k_lin64(const float* __restrict__ A,
    const unsigned short* __restrict__ Wh, const unsigned short* __restrict__ Wl,
    const float* __restrict__ bias, float* __restrict__ out){
  __shared__ unsigned short sAh[64*PAD];
  __shared__ unsigned short sAl[64*PAD];
  int t = threadIdx.x;
  int v0 = blockIdx.x * 64;
  int lane = t & 63, w = t >> 6;
  int wm = w & 1, wn = w >> 1;
  int lr = lane & 15, lk = lane >> 4;
  int bbase[4];
  #pragma unroll
  for (int n=0;n<4;n++) bbase[n] = (wn*64 + n*16 + lr)*128 + lk*8;
  f32x4 acc[2][4];
  #pragma unroll
  for (int m=0;m<2;m++)
    #pragma unroll
    for (int n=0;n<4;n++) acc[m][n] = (f32x4)(0.f);

  for (int kb = 0; kb < 128; kb += 64){
    #pragma unroll
    for (int i=0;i<4;i++){
      int u = t + i*256, row = u >> 4, slot = u & 15;
      float4 va = *(const float4*)(A + (size_t)(v0+row)*128 + kb + slot*4);
      unsigned int p0 = split2p(va.x), p1 = split2p(va.y);
      unsigned int p2 = split2p(va.z), p3 = split2p(va.w);
      ushort4v hi, lo;
      hi[0]=(unsigned short)p0; lo[0]=(unsigned short)(p0>>16);
      hi[1]=(unsigned short)p1; lo[1]=(unsigned short)(p1>>16);
      hi[2]=(unsigned short)p2; lo[2]=(unsigned short)(p2>>16);
      hi[3]=(unsigned short)p3; lo[3]=(unsigned short)(p3>>16);
      *(ushort4v*)&sAh[row*PAD + slot*4] = hi;
      *(ushort4v*)&sAl[row*PAD + slot*4] = lo;
    }
    __syncthreads();
    #pragma unroll
    for (int kk=0; kk<64; kk+=32){
      bf16x8 ah[2], al[2], bh[4], bl[4];
      #pragma unroll
      for (int m=0;m<2;m++){
        ah[m] = *(const bf16x8*)&sAh[(wm*32 + m*16 + lr)*PAD + kk + lk*8];
        al[m] = *(const bf16x8*)&sAl[(wm*32 + m*16 + lr)*PAD + kk + lk*8];
      }
      #pragma unroll
      for (int n=0;n<4;n++){
        bh[n] = *(const bf16x8*)(Wh + bbase[n] + kb + kk);
        bl[n] = *(const bf16x8*)(Wl + bbase[n] + kb + kk);
      }
      #pragma unroll
      for (int m=0;m<2;m++)
        #pragma unroll
        for (int n=0;n<4;n++){
          acc[m][n] = __builtin_amdgcn_mfma_f32_16x16x32_bf16(ah[m], bh[n], acc[m][n], 0, 0, 0);
          acc[m][n] = __builtin_amdgcn_mfma_f32_16x16x32_bf16(al[m], bh[n], acc[m][n], 0, 0, 0);
          acc[m][n] = __builtin_amdgcn_mfma_f32_16x16x32_bf16(ah[m], bl[n], acc[m][n], 0, 0, 0);
        }
    }
    __syncthreads();
  }

  #pragma unroll
  for (int m=0;m<2;m++){
    #pragma unroll
    for (int n=0;n<4;n++){
      int col = wn*64 + n*16 + lr;
      float bb = bias ? bias[col] : 0.f;
      #pragma unroll
      for (int r=0;r<4;r++){
        int row = v0 + wm*32 + m*16 + lk*4 + r;
        float val = acc[m][n][r] + bb;
        if (OUT_MODE == 2) val = leaky(val);
        out[(size_t)row*128 + col] = val;
      }
    }
  }
}

// ======== fused pre GEMM: Pd = A@Wd, Ps = A@Ws; Wt combined [128][256] hi/lo ========

__global__ __launch_bounds__(256) void k_pre64(const float* __restrict__ A,
    const unsigned short* __restrict__ Wh, const unsigned short* __restrict__ Wl,
    float* __restrict__ Pd, float* __restrict__ Ps){
  __shared__ unsigned short sAh[64*PAD];
  __shared__ unsigned short sAl[64*PAD];
  int t = threadIdx.x;
  int bid = blockIdx.x;
  int rowt = bid >> 1, colt = bid & 1;
  int v0 = rowt * 64;
  int lane = t & 63, w = t >> 6;
  int wm = w & 1, wn = w >> 1;
  int lr = lane & 15, lk = lane >> 4;
  int brow0 = (colt*64 + wn*32 + lr)*256 + lk*8;
  int brow1 = brow0 + 16*256;
  f32x4 accd[2][2], accs[2][2];
  #pragma unroll
  for (int m=0;m<2;m++)
    #pragma unroll
    for (int n=0;n<2;n++){ accd[m][n] = (f32x4)(0.f); accs[m][n] = (f32x4)(0.f); }

  for (int kb = 0; kb < 128; kb += 64){
    #pragma unroll
    for (int i=0;i<4;i++){
      int u = t + i*256, row = u >> 4, slot = u & 15;
      float4 va = *(const float4*)(A + (size_t)(v0+row)*128 + kb + slot*4);
      unsigned int p0 = split2p(va.x), p1 = split2p(va.y);
      unsigned int p2 = split2p(va.z), p3 = split2p(va.w);
      ushort4v hi, lo;
      hi[0]=(unsigned short)p0; lo[0]=(unsigned short)(p0>>16);
      hi[1]=(unsigned short)p1; lo[1]=(unsigned short)(p1>>16);
      hi[2]=(unsigned short)p2; lo[2]=(unsigned short)(p2>>16);
      hi[3]=(unsigned short)p3; lo[3]=(unsigned short)(p3>>16);
      *(ushort4v*)&sAh[row*PAD + slot*4] = hi;
      *(ushort4v*)&sAl[row*PAD + slot*4] = lo;
    }
    __syncthreads();
    #pragma unroll
    for (int kk=0; kk<64; kk+=32){
      bf16x8 ah[2], al[2], bh[2], bl[2];
      #pragma unroll
      for (int m=0;m<2;m++){
        ah[m] = *(const bf16x8*)&sAh[(wm*32 + m*16 + lr)*PAD + kk + lk*8];
        al[m] = *(const bf16x8*)&sAl[(wm*32 + m*16 + lr)*PAD + kk + lk*8];
      }
      bh[0] = *(const bf16x8*)(Wh + brow0 + kb + kk);
      bh[1] = *(const bf16x8*)(Wh + brow1 + kb + kk);
      bl[0] = *(const bf16x8*)(Wl + brow0 + kb + kk);
      bl[1] = *(const bf16x8*)(Wl + brow1 + kb + kk);
      #pragma unroll
      for (int m=0;m<2;m++)
        #pragma unroll
        for (int n=0;n<2;n++){
          accd[m][n] = __builtin_amdgcn_mfma_f32_16x16x32_bf16(ah[m], bh[n], accd[m][n], 0, 0, 0);
          accd[m][n] = __builtin_amdgcn_mfma_f32_16x16x32_bf16(al[m], bh[n], accd[m][n], 0, 0, 0);
          accd[m][n] = __builtin_amdgcn_mfma_f32_16x16x32_bf16(ah[m], bl[n], accd[m][n], 0, 0, 0);
        }
      bh[0] = *(const bf16x8*)(Wh + brow0 + 128 + kb + kk);
      bh[1] = *(const bf16x8*)(Wh + brow1 + 128 + kb + kk);
      bl[0] = *(const bf16x8*)(Wl + brow0 + 128 + kb + kk);
      bl[1] = *(const bf16x8*)(Wl + brow1 + 128 + kb + kk);
      #pragma unroll
      for (int m=0;m<2;m++)
        #pragma unroll
        for (int n=0;n<2;n++){
          accs[m][n] = __builtin_amdgcn_mfma_f32_16x16x32_bf16(ah[m], bh[n], accs[m][n], 0, 0, 0);
          accs[m][n] = __builtin_amdgcn_mfma_f32_16x16x32_bf16(al[m], bh[n], accs[m][n], 0, 0, 0);
          accs[m][n] = __builtin_amdgcn_mfma_f32_16x16x32_bf16(ah[m], bl[n], accs[m][n], 0, 0, 0);
        }
    }
    __syncthreads();
  }

  #pragma unroll
  for (int m=0;m<2;m++){
    #pragma unroll
    for (int n=0;n<2;n++){
      int col = colt*64 + wn*32 + n*16 + lr;
      #pragma unroll
      for (int r=0;r<4;r++){
        int row = v0 + wm*32 + m*16 + lk*4 + r;
        Pd[(size_t)row*128 + col] = accd[m][n][r];
        Ps[(size_t)row*128 + col] = accs[m][n][r];
      }
    }
  }
}

// ---------------- aggregation (H=128), f32 out, 2 nodes/block, unroll-4 ----------------

__global__ __launch_bounds__(256) void k_agg(const float* __restrict__ Pd, const float* __restrict__ Ps,
                      const float* __restrict__ pre_b, const int* __restrict__ offs,
                      const int* __restrict__ deg, const int* __restrict__ csr,
                      float* __restrict__ aggf){
  int t = threadIdx.x;
  int v = blockIdx.x*2 + (t >> 7);
  int f = t & 127;
  int off = offs[v], d = deg[v];
  float hb = Pd[(size_t)v*128 + f] + pre_b[f];
  float s=0.f, q=0.f, mx=-INFINITY, mn=INFINITY;
  int i = 0;
  for (; i+4 <= d; i += 4){
    int i0 = csr[off+i], i1 = csr[off+i+1], i2 = csr[off+i+2], i3 = csr[off+i+3];
    float h0 = hb + Ps[(size_t)i0*128 + f];
    float h1 = hb + Ps[(size_t)i1*128 + f];
    float h2 = hb + Ps[(size_t)i2*128 + f];
    float h3 = hb + Ps[(size_t)i3*128 + f];
    s += (h0+h1) + (h2+h3);
    q = fmaf(h0,h0, fmaf(h1,h1, fmaf(h2,h2, fmaf(h3,h3, q))));
    mx = fmaxf(fmaxf(fmaxf(mx,h0),fmaxf(h1,h2)),h3);
    mn = fminf(fminf(fminf(mn,h0),fminf(h1,h2)),h3);
  }
  for (; i < d; i++){
    int sv = csr[off+i];
    float h = hb + Ps[(size_t)sv*128 + f];
    s += h; q = fmaf(h,h,q);
    mx = fmaxf(mx, h); mn = fminf(mn, h);
  }
  float degc = fmaxf((float)d, 1.f);
  float mean = s/degc;
  float stdv = sqrtf(fmaxf(q/degc - mean*mean, 0.f) + 1e-5f);
  if (d == 0){ mx = 0.f; mn = 0.f; }
  size_t o = (size_t)v*512;
  aggf[o+f]      = mean;
  aggf[o+128+f]  = stdv;
  aggf[o+256+f]  = mx;
  aggf[o+384+f]  = mn;
}

// ======== post GEMM (scaling commuted to epilogue): A read ONCE ========
// out = state@W0 + agg@W1 + amp*(agg@W2) + att*(agg@W3)
// grid V/64, block 512 = 8 waves; wave w covers cols w*16 (16 cols each).
// Per-wave MFMA:B-load ratio 6:1 (as R9) but 2x waves/SIMD for latency hiding.
// Wt regions in [128][1664]: W0 @ k=0, W1 @ 128, W2 @ 640, W3 @ 1152.

__global__ __launch_bounds__(512) void k_postY(const float* __restrict__ state,
    const float* __restrict__ aggf, const float* __restrict__ amp, const float* __restrict__ att,
    const unsigned short* __restrict__ Wh, const unsigned short* __restrict__ Wl,
    const float* __restrict__ bias, float* __restrict__ out){
  __shared__ unsigned short sAh[64*PAD];
  __shared__ unsigned short sAl[64*PAD];
  __shared__ float sScl[2][64];
  int t = threadIdx.x;
  int v0 = blockIdx.x * 64;
  if (t < 64) sScl[0][t] = amp[v0+t];
  else if (t < 128) sScl[1][t-64] = att[v0+t-64];
  int lane = t & 63, w = t >> 6;     // wave w (0..7): cols w*16 .. w*16+15
  int lr = lane & 15, lk = lane >> 4;
  int bb0 = (w*16 + lr)*1664 + lk*8;
  f32x4 a1[4], a2[4], a3[4];
  #pragma unroll
  for (int m=0;m<4;m++){ a1[m]=(f32x4)(0.f); a2[m]=(f32x4)(0.f); a3[m]=(f32x4)(0.f); }

  // ---- state part: K = 128, W0 region ----
  for (int kb = 0; kb < 128; kb += 64){
    #pragma unroll
    for (int i=0;i<2;i++){
      int u = t + i*512, row = u >> 4, slot = u & 15;
      float4 va = *(const float4*)(state + (size_t)(v0+row)*128 + kb + slot*4);
      unsigned int p0 = split2p(va.x), p1 = split2p(va.y);
      unsigned int p2 = split2p(va.z), p3 = split2p(va.w);
      ushort4v hi, lo;
      hi[0]=(unsigned short)p0; lo[0]=(unsigned short)(p0>>16);
      hi[1]=(unsigned short)p1; lo[1]=(unsigned short)(p1>>16);
      hi[2]=(unsigned short)p2; lo[2]=(unsigned short)(p2>>16);
      hi[3]=(unsigned short)p3; lo[3]=(unsigned short)(p3>>16);
      *(ushort4v*)&sAh[row*PAD + slot*4] = hi;
      *(ushort4v*)&sAl[row*PAD + slot*4] = lo;
    }
    __syncthreads();
    #pragma unroll
    for (int kk=0; kk<64; kk+=32){
      bf16x8 ah[4], al[4], bh, bl;
      #pragma unroll
      for (int m=0;m<4;m++){
        ah[m] = *(const bf16x8*)&sAh[(m*16 + lr)*PAD + kk + lk*8];
        al[m] = *(const bf16x8*)&sAl[(m*16 + lr)*PAD + kk + lk*8];
      }
      bh = *(const bf16x8*)(Wh + bb0 + kb + kk);
      bl = *(const bf16x8*)(Wl + bb0 + kb + kk);
      #pragma unroll
      for (int m=0;m<4;m++){
        a1[m] = __builtin_amdgcn_mfma_f32_16x16x32_bf16(ah[m], bh, a1[m], 0, 0, 0);
        a1[m] = __builtin_amdgcn_mfma_f32_16x16x32_bf16(al[m], bh, a1[m], 0, 0, 0);
        a1[m] = __builtin_amdgcn_mfma_f32_16x16x32_bf16(ah[m], bl, a1[m], 0, 0, 0);
      }
    }
    __syncthreads();
  }

  // ---- agg part: K = 512, W1/W2/W3 regions on the SAME staged A ----
  for (int kb = 0; kb < 512; kb += 64){
    #pragma unroll
    for (int i=0;i<2;i++){
      int u = t + i*512, row = u >> 4, slot = u & 15;
      float4 va = *(const float4*)(aggf + (size_t)(v0+row)*512 + kb + slot*4);
      unsigned int p0 = split2p(va.x), p1 = split2p(va.y);
      unsigned int p2 = split2p(va.z), p3 = split2p(va.w);
      ushort4v hi, lo;
      hi[0]=(unsigned short)p0; lo[0]=(unsigned short)(p0>>16);
      hi[1]=(unsigned short)p1; lo[1]=(unsigned short)(p1>>16);
      hi[2]=(unsigned short)p2; lo[2]=(unsigned short)(p2>>16);
      hi[3]=(unsigned short)p3; lo[3]=(unsigned short)(p3>>16);
      *(ushort4v*)&sAh[row*PAD + slot*4] = hi;
      *(ushort4v*)&sAl[row*PAD + slot*4] = lo;
    }
    __syncthreads();
    #pragma unroll
    for (int kk=0; kk<64; kk+=32){
      bf16x8 ah[4], al[4];
      #pragma unroll
      for (int m=0;m<4;m++){
        ah[m] = *(const bf16x8*)&sAh[(m*16 + lr)*PAD + kk + lk*8];
        al[m] = *(const bf16x8*)&sAl[(m*16 + lr)*PAD + kk + lk*8];
      }
      #pragma unroll
      for (int j=0;j<3;j++){
        int off = 128 + j*512 + kb + kk;
        bf16x8 bh = *(const bf16x8*)(Wh + bb0 + off);
        bf16x8 bl = *(const bf16x8*)(Wl + bb0 + off);
        #pragma unroll
        for (int m=0;m<4;m++){
          f32x4 acc = (j==0) ? a1[m] : (j==1) ? a2[m] : a3[m];
          acc = __builtin_amdgcn_mfma_f32_16x16x32_bf16(ah[m], bh, acc, 0, 0, 0);
          acc = __builtin_amdgcn_mfma_f32_16x16x32_bf16(al[m], bh, acc, 0, 0, 0);
          acc = __builtin_amdgcn_mfma_f32_16x16x32_bf16(ah[m], bl, acc, 0, 0, 0);
          if (j==0) a1[m] = acc; else if (j==1) a2[m] = acc; else a3[m] = acc;
        }
      }
    }
    __syncthreads();
  }

  // ---- epilogue: out = a1 + bias + amp*a2 + att*a3 ----
  int col = w*16 + lr;
  float bbv = bias[col];
  #pragma unroll
  for (int m=0;m<4;m++){
    #pragma unroll
    for (int r=0;r<4;r++){
      int rl = m*16 + lk*4 + r;
      float val = a1[m][r] + bbv + sScl[0][rl]*a2[m][r] + sScl[1][rl]*a3[m][r];
      out[(size_t)(v0+rl)*128 + col] = val;
    }
  }
}

// ---------------- readout tail ----------------

__global__ void k_tail(const float* __restrict__ h1, const float* __restrict__ r2_w,
                       const float* __restrict__ r2_b, const float* __restrict__ r3_w,
                       const float* __restrict__ r3_b, const float* __restrict__ target_n,
                       float* __restrict__ out, float* __restrict__ gacc){
  __shared__ float sh[16][129];
  __shared__ float h2[16][8];
  __shared__ float red[128];
  int t = threadIdx.x; // 128
  int v0 = blockIdx.x * 16;
  for (int r=0;r<16;r++) sh[r][t] = h1[(size_t)(v0+r)*128 + t];
  __syncthreads();
  int n = t >> 3, o = t & 7;
  float acc = r2_b[o];
  for (int k=0;k<128;k++) acc = fmaf(sh[n][k], r2_w[k*8+o], acc);
  h2[n][o] = leaky(acc);
  __syncthreads();
  float err = 0.f;
  if (t < 48){
    int n3 = t / 3, o3 = t % 3;
    float a = r3_b[o3];
    #pragma unroll
    for (int k=0;k<8;k++) a = fmaf(h2[n3][k], r3_w[k*3+o3], a);
    a = leaky(a);
    int v = v0 + n3;
    out[(size_t)v*3 + o3] = a;
    float d = a - target_n[(size_t)v*3 + o3];
    err = d*d;
  }
  red[t] = err; __syncthreads();
  for (int s=64;s>0;s>>=1){ if (t<s) red[t]+=red[t+s]; __syncthreads(); }
  if (t==0) atomicAdd(&gacc[v0 / NN], red[0]);
}

__global__ void k_finalize(const float* __restrict__ gacc, float* __restrict__ out){
  __shared__ float red[128];
  int t = threadIdx.x; // 128
  float a = gacc[t];
  out[(size_t)V*3 + 1 + t] = a / (float)(NN*3);
  red[t] = a; __syncthreads();
  for (int s=64;s>0;s>>=1){ if (t<s) red[t]+=red[t+s]; __syncthreads(); }
  if (t==0) out[(size_t)V*3] = red[0] / (float)(V*3);
}

// ---------------- launch ----------------

extern "C" void kernel_launch(void* const* d_in, const int* in_sizes, int n_in,
                              void* d_out, int out_size, void* d_ws, size_t ws_size,
                              hipStream_t stream){
  const float* x        = (const float*)d_in[0];
  const int*   ei       = (const int*)d_in[1];
  const float* target_n = (const float*)d_in[2];
  const float* pre1_w = (const float*)d_in[4];
  const float* pre1_b = (const float*)d_in[5];
  const float* post1_w= (const float*)d_in[6];
  const float* post1_b= (const float*)d_in[7];
  const float* lin1_w = (const float*)d_in[8];
  const float* lin1_b = (const float*)d_in[9];
  const float* pre_w  = (const float*)d_in[10];
  const float* pre_b  = (const float*)d_in[11];
  const float* post_w = (const float*)d_in[12];
  const float* post_b = (const float*)d_in[13];
  const float* lin_w  = (const float*)d_in[14];
  const float* lin_b  = (const float*)d_in[15];
  const float* r1_w = (const float*)d_in[16];
  const float* r1_b = (const float*)d_in[17];
  const float* r2_w = (const float*)d_in[18];
  const float* r2_b = (const float*)d_in[19];
  const float* r3_w = (const float*)d_in[20];
  const float* r3_b = (const float*)d_in[21];
  float* out = (float*)d_out;

  char* wp = (char*)d_ws;
  auto alloc = [&](size_t bytes){ void* p = (void*)wp; wp += (bytes + 255) & ~(size_t)255; return p; };
  // zero region must stay contiguous: deg, cursor, avg_acc, gacc
  int*   deg     = (int*)  alloc((size_t)V*4);
  int*   cursor  = (int*)  alloc((size_t)V*4);
  float* avg_acc = (float*)alloc(4);
  float* gacc    = (float*)alloc((size_t)NB*4);
  int*   offs    = (int*)  alloc((size_t)(V+1)*4);
  int*   csr     = (int*)  alloc((size_t)E*4);
  float* amp     = (float*)alloc((size_t)V*4);
  float* att     = (float*)alloc((size_t)V*4);
  float* Pd      = (float*)alloc((size_t)V*H*4);
  float* Ps      = (float*)alloc((size_t)V*H*4);
  float* aggf    = (float*)alloc((size_t)V*512*4);     // 64 MB; layer-1 scratch aliases in here
  float* tmpf    = (float*)alloc((size_t)V*H*4);
  float* stA     = (float*)alloc((size_t)V*H*4);
  float* stB     = (float*)alloc((size_t)V*H*4);
  unsigned short* wt_pre_h   = (unsigned short*)alloc((size_t)H*2*H*2);  // [128][256]
  unsigned short* wt_pre_l   = (unsigned short*)alloc((size_t)H*2*H*2);
  unsigned short* wt_lin_h   = (unsigned short*)alloc((size_t)H*H*2);
  unsigned short* wt_lin_l   = (unsigned short*)alloc((size_t)H*H*2);
  unsigned short* wt_lin1_h  = (unsigned short*)alloc((size_t)H*H*2);
  unsigned short* wt_lin1_l  = (unsigned short*)alloc((size_t)H*H*2);
  unsigned short* wt_r1_h    = (unsigned short*)alloc((size_t)H*H*2);
  unsigned short* wt_r1_l    = (unsigned short*)alloc((size_t)H*H*2);
  unsigned short* wt_post_h  = (unsigned short*)alloc((size_t)13*H*H*2);
  unsigned short* wt_post_l  = (unsigned short*)alloc((size_t)13*H*H*2);

  // layer-1 scratch aliased into aggf (used strictly before first k_agg)
  float* agg1 = aggf;                                  // V*8 f32 = 1 MB
  float* in26 = aggf + (size_t)V*8;                    // V*26 f32 = 3.4 MB

  int zeroN = (int)(((char*)offs - (char*)deg) / 4);
  k_zero_i<<<(zeroN+255)/256, 256, 0, stream>>>(deg, zeroN);
  k_deg<<<E/256, 256, 0, stream>>>(ei, deg);
  k_scan<<<1, 1024, 0, stream>>>(deg, offs);
  k_avglog<<<V/256, 256, 0, stream>>>(deg, avg_acc);
  k_ampatt<<<V/256, 256, 0, stream>>>(deg, avg_acc, amp, att);
  k_fill<<<E/256, 256, 0, stream>>>(ei, offs, cursor, csr);

  // weight prep (bf16 hi/lo, transposed)
  {
    dim3 b(32,8);
    k_wt2<<<dim3(8,4),  b, 0, stream>>>(pre_w,   wt_pre_h,  wt_pre_l, 256, 128);  // [256,128] -> [128][256]
    k_wt2<<<dim3(52,4), b, 0, stream>>>(post_w,  wt_post_h, wt_post_l, 1664, 128);
    k_wt2<<<dim3(4,4),  b, 0, stream>>>(lin_w,   wt_lin_h,  wt_lin_l,  128, 128);
    k_wt2<<<dim3(4,4),  b, 0, stream>>>(lin1_w,  wt_lin1_h, wt_lin1_l, 128, 128);
    k_wt2<<<dim3(4,4),  b, 0, stream>>>(r1_w,    wt_r1_h,   wt_r1_l,   128, 128);
  }

  // layer 1 (F=2) — all f32
  k_l1_proj<<<V/256, 256, 0, stream>>>(x, pre1_w, Pd, Ps);
  k_l1_agg<<<V/256, 256, 0, stream>>>(Pd, Ps, pre1_b, offs, deg, csr, agg1);
  k_l1_in26<<<V/256, 256, 0, stream>>>(x, agg1, amp, att, in26);
  k_gemm26<<<V/16, 128, 0, stream>>>(in26, post1_w, post1_b, tmpf);
  k_lin64<0><<<V/64, 256, 0, stream>>>(tmpf, wt_lin1_h, wt_lin1_l, lin1_b, stA);

  // 3 propagation layers (H=128)
  float* cur = stA;
  float* nxt = stB;
  for (int l=0; l<3; l++){
    k_pre64<<<(V/64)*2, 256, 0, stream>>>(cur, wt_pre_h, wt_pre_l, Pd, Ps);
    k_agg<<<V/2, 256, 0, stream>>>(Pd, Ps, pre_b, offs, deg, csr, aggf);
    k_postY<<<V/64, 512, 0, stream>>>(cur, aggf, amp, att, wt_post_h, wt_post_l, post_b, tmpf);
    k_lin64<0><<<V/64, 256, 0, stream>>>(tmpf, wt_lin_h, wt_lin_l, lin_b, nxt);
    float* t2 = cur; cur = nxt; nxt = t2;
  }

  // readout
  k_lin64<2><<<V/64, 256, 0, stream>>>(cur, wt_r1_h, wt_r1_l, r1_b, tmpf);
  k_tail<<<V/16, 128, 0, stream>>>(tmpf, r2_w, r2_b, r3_w, r3_b, target_n, out, gacc);
  k_finalize<<<1, 128, 0, stream>>>(gacc, out);
}

// Round 12
// 654.600 us; speedup vs baseline: 1.3359x; 1.0461x over previous
//
#include <hip/hip_runtime.h>
#include <hip/hip_bf16.h>
#include <math.h>

constexpr int V = 32768;
constexpr int E = 524288;
constexpr int H = 128;
constexpr int NB = 128;   // graphs per batch
constexpr int NN = 256;   // nodes per graph
constexpr int PAD = 68;   // LDS row pitch (shorts), stage-1
constexpr int PAD2 = 136; // LDS row pitch (shorts), fused lin stage (128 cols + pad)

typedef short bf16x8 __attribute__((ext_vector_type(8)));
typedef float f32x4 __attribute__((ext_vector_type(4)));
typedef unsigned short ushort8 __attribute__((ext_vector_type(8)));
typedef unsigned short ushort4v __attribute__((ext_vector_type(4)));

static __device__ __forceinline__ float leaky(float x){ return x > 0.f ? x : 0.01f*x; }
static __device__ __forceinline__ float b2f(unsigned short u){
  unsigned int x = ((unsigned int)u) << 16; return __uint_as_float(x);
}
static __device__ __forceinline__ unsigned short f2b(float f){
  union { __hip_bfloat16 h; unsigned short u; } cv;
  cv.h = __float2bfloat16(f);
  return cv.u;
}
// split f32 into hi + lo bf16; packed low16=hi, high16=lo
static __device__ __forceinline__ unsigned int split2p(float f){
  unsigned short hh = f2b(f);
  float r = f - b2f(hh);
  unsigned short ll = f2b(r);
  return (unsigned int)hh | ((unsigned int)ll << 16);
}

// ---------------- setup kernels ----------------

__global__ void k_zero_i(int* __restrict__ p, int n){
  int i = blockIdx.x*blockDim.x + threadIdx.x;
  if (i < n) p[i] = 0;
}

__global__ void k_deg(const int* __restrict__ ei, int* __restrict__ deg){
  int e = blockIdx.x*blockDim.x + threadIdx.x;
  if (e < E) atomicAdd(&deg[ei[E+e]], 1);
}

__global__ void k_scan(const int* __restrict__ deg, int* __restrict__ offs){
  __shared__ int partial[1024];
  int t = threadIdx.x;
  int base = t*32;
  int local[32];
  int s = 0;
  #pragma unroll
  for (int i=0;i<32;i++){ local[i] = s; s += deg[base+i]; }
  partial[t] = s;
  __syncthreads();
  for (int o=1;o<1024;o<<=1){
    int v = (t>=o) ? partial[t-o] : 0;
    __syncthreads();
    partial[t] += v;
    __syncthreads();
  }
  int excl = (t==0) ? 0 : partial[t-1];
  #pragma unroll
  for (int i=0;i<32;i++) offs[base+i] = excl + local[i];
  if (t==1023) offs[V] = excl + s;
}

__global__ void k_avglog(const int* __restrict__ deg, float* __restrict__ avg_acc){
  int v = blockIdx.x*blockDim.x + threadIdx.x;
  float l = (v < V) ? logf((float)deg[v] + 1.f) : 0.f;
  __shared__ float red[256];
  int t = threadIdx.x;
  red[t] = l; __syncthreads();
  for (int s=128;s>0;s>>=1){ if (t<s) red[t]+=red[t+s]; __syncthreads(); }
  if (t==0) atomicAdd(avg_acc, red[0]);
}

__global__ void k_ampatt(const int* __restrict__ deg, const float* __restrict__ avg_acc,
                         float* __restrict__ amp, float* __restrict__ att){
  int v = blockIdx.x*blockDim.x + threadIdx.x;
  if (v >= V) return;
  float avg = avg_acc[0] * (1.f/(float)V);
  float degc = fmaxf((float)deg[v], 1.f);
  float logd = logf(degc + 1.f);
  amp[v] = logd / avg;
  att[v] = avg / logd;
}

__global__ void k_fill(const int* __restrict__ ei, const int* __restrict__ offs,
                       int* __restrict__ cursor, int* __restrict__ csr){
  int e = blockIdx.x*blockDim.x + threadIdx.x;
  if (e >= E) return;
  int d = ei[E+e];
  int slot = atomicAdd(&cursor[d], 1);
  csr[offs[d] + slot] = ei[e];
}

// ---------------- weight prep: W[K][N] f32 -> Wt_hi/Wt_lo [N][K] bf16 ----------------

__global__ void k_wt2(const float* __restrict__ W, unsigned short* __restrict__ Wh,
                      unsigned short* __restrict__ Wl, int K, int N){
  __shared__ float tile[32][33];
  int kb = blockIdx.x*32, nb = blockIdx.y*32;
  int tx = threadIdx.x, ty = threadIdx.y;   // (32,8)
  #pragma unroll
  for (int i=0;i<4;i++) tile[ty+8*i][tx] = W[(size_t)(kb+ty+8*i)*N + nb+tx];
  __syncthreads();
  #pragma unroll
  for (int i=0;i<4;i++){
    int n = ty+8*i;
    unsigned int p = split2p(tile[tx][n]);
    Wh[(size_t)(nb+n)*K + kb+tx] = (unsigned short)(p & 0xffff);
    Wl[(size_t)(nb+n)*K + kb+tx] = (unsigned short)(p >> 16);
  }
}

// ---------------- layer 1 (F=2) ----------------

__global__ void k_l1_proj(const float* __restrict__ x, const float* __restrict__ pre1_w,
                          float* __restrict__ Pd2, float* __restrict__ Ps2){
  int v = blockIdx.x*blockDim.x + threadIdx.x;
  if (v >= V) return;
  float x0 = x[v*2], x1 = x[v*2+1];
  Pd2[v*2+0] = x0*pre1_w[0] + x1*pre1_w[2];
  Pd2[v*2+1] = x0*pre1_w[1] + x1*pre1_w[3];
  Ps2[v*2+0] = x0*pre1_w[4] + x1*pre1_w[6];
  Ps2[v*2+1] = x0*pre1_w[5] + x1*pre1_w[7];
}

__global__ void k_l1_agg(const float* __restrict__ Pd2, const float* __restrict__ Ps2,
                         const float* __restrict__ pre1_b,
                         const int* __restrict__ offs, const int* __restrict__ deg,
                         const int* __restrict__ csr, float* __restrict__ agg1){
  int v = blockIdx.x*blockDim.x + threadIdx.x;
  if (v >= V) return;
  int off = offs[v], d = deg[v];
  float hb0 = Pd2[v*2]   + pre1_b[0];
  float hb1 = Pd2[v*2+1] + pre1_b[1];
  float s0=0.f,s1=0.f,q0=0.f,q1=0.f;
  float mx0=-INFINITY,mx1=-INFINITY,mn0=INFINITY,mn1=INFINITY;
  for (int i=0;i<d;i++){
    int s = csr[off+i];
    float h0 = hb0 + Ps2[s*2];
    float h1 = hb1 + Ps2[s*2+1];
    s0+=h0; s1+=h1; q0+=h0*h0; q1+=h1*h1;
    mx0=fmaxf(mx0,h0); mx1=fmaxf(mx1,h1);
    mn0=fminf(mn0,h0); mn1=fminf(mn1,h1);
  }
  float degc = fmaxf((float)d, 1.f);
  float m0 = s0/degc, m1 = s1/degc;
  float sd0 = sqrtf(fmaxf(q0/degc - m0*m0, 0.f) + 1e-5f);
  float sd1 = sqrtf(fmaxf(q1/degc - m1*m1, 0.f) + 1e-5f);
  if (d == 0){ mx0=0.f; mx1=0.f; mn0=0.f; mn1=0.f; }
  float* o = agg1 + (size_t)v*8;
  o[0]=m0; o[1]=m1; o[2]=sd0; o[3]=sd1; o[4]=mx0; o[5]=mx1; o[6]=mn0; o[7]=mn1;
}

__global__ void k_l1_in26(const float* __restrict__ x, const float* __restrict__ agg1,
                          const float* __restrict__ amp, const float* __restrict__ att,
                          float* __restrict__ in26){
  int v = blockIdx.x*blockDim.x + threadIdx.x;
  if (v >= V) return;
  float a = amp[v], t = att[v];
  float* o = in26 + (size_t)v*26;
  o[0] = x[v*2]; o[1] = x[v*2+1];
  #pragma unroll
  for (int i=0;i<8;i++){
    float g = agg1[(size_t)v*8 + i];
    o[2+i] = g; o[10+i] = g*a; o[18+i] = g*t;
  }
}

__global__ void k_gemm26(const float* __restrict__ in26, const float* __restrict__ Wp,
                         const float* __restrict__ bias, float* __restrict__ out){
  __shared__ float sin26[16][27];
  int t = threadIdx.x; // 128
  int v0 = blockIdx.x * 16;
  for (int idx = t; idx < 16*26; idx += 128){
    int r = idx / 26, c = idx % 26;
    sin26[r][c] = in26[(size_t)(v0+r)*26 + c];
  }
  __syncthreads();
  float acc[16];
  #pragma unroll
  for (int r=0;r<16;r++) acc[r] = 0.f;
  for (int k=0;k<26;k++){
    float wv = Wp[k*128 + t];
    #pragma unroll
    for (int r=0;r<16;r++) acc[r] = fmaf(sin26[r][k], wv, acc[r]);
  }
  float bb = bias[t];
  for (int r=0;r<16;r++) out[(size_t)(v0+r)*128 + t] = acc[r] + bb;
}

// ======== full-N 64x128 split-precision MFMA GEMM (A read once), B from global(L2) ========
// grid V/64; 4 waves 2x2, each 32x64. acc += Ah*Wh + Al*Wh + Ah*Wl.

template<int OUT_MODE> // 0 = f32, 2 = f32 + leaky
__global__ __launch_bounds__(256) void k_lin64(const float* __restrict__ A,
    const unsigned short* __restrict__ Wh, const unsigned short* __restrict__ Wl,
    const float* __restrict__ bias, float* __restrict__ out){
  __shared__ unsigned short sAh[64*PAD];
  __shared__ unsigned short sAl[64*PAD];
  int t = threadIdx.x;
  int v0 = blockIdx.x * 64;
  int lane = t & 63, w = t >> 6;
  int wm = w & 1, wn = w >> 1;
  int lr = lane & 15, lk = lane >> 4;
  int bbase[4];
  #pragma unroll
  for (int n=0;n<4;n++) bbase[n] = (wn*64 + n*16 + lr)*128 + lk*8;
  f32x4 acc[2][4];
  #pragma unroll
  for (int m=0;m<2;m++)
    #pragma unroll
    for (int n=0;n<4;n++) acc[m][n] = (f32x4)(0.f);

  for (int kb = 0; kb < 128; kb += 64){
    #pragma unroll
    for (int i=0;i<4;i++){
      int u = t + i*256, row = u >> 4, slot = u & 15;
      float4 va = *(const float4*)(A + (size_t)(v0+row)*128 + kb + slot*4);
      unsigned int p0 = split2p(va.x), p1 = split2p(va.y);
      unsigned int p2 = split2p(va.z), p3 = split2p(va.w);
      ushort4v hi, lo;
      hi[0]=(unsigned short)p0; lo[0]=(unsigned short)(p0>>16);
      hi[1]=(unsigned short)p1; lo[1]=(unsigned short)(p1>>16);
      hi[2]=(unsigned short)p2; lo[2]=(unsigned short)(p2>>16);
      hi[3]=(unsigned short)p3; lo[3]=(unsigned short)(p3>>16);
      *(ushort4v*)&sAh[row*PAD + slot*4] = hi;
      *(ushort4v*)&sAl[row*PAD + slot*4] = lo;
    }
    __syncthreads();
    #pragma unroll
    for (int kk=0; kk<64; kk+=32){
      bf16x8 ah[2], al[2], bh[4], bl[4];
      #pragma unroll
      for (int m=0;m<2;m++){
        ah[m] = *(const bf16x8*)&sAh[(wm*32 + m*16 + lr)*PAD + kk + lk*8];
        al[m] = *(const bf16x8*)&sAl[(wm*32 + m*16 + lr)*PAD + kk + lk*8];
      }
      #pragma unroll
      for (int n=0;n<4;n++){
        bh[n] = *(const bf16x8*)(Wh + bbase[n] + kb + kk);
        bl[n] = *(const bf16x8*)(Wl + bbase[n] + kb + kk);
      }
      #pragma unroll
      for (int m=0;m<2;m++)
        #pragma unroll
        for (int n=0;n<4;n++){
          acc[m][n] = __builtin_amdgcn_mfma_f32_16x16x32_bf16(ah[m], bh[n], acc[m][n], 0, 0, 0);
          acc[m][n] = __builtin_amdgcn_mfma_f32_16x16x32_bf16(al[m], bh[n], acc[m][n], 0, 0, 0);
          acc[m][n] = __builtin_amdgcn_mfma_f32_16x16x32_bf16(ah[m], bl[n], acc[m][n], 0, 0, 0);
        }
    }
    __syncthreads();
  }

  #pragma unroll
  for (int m=0;m<2;m++){
    #pragma unroll
    for (int n=0;n<4;n++){
      int col = wn*64 + n*16 + lr;
      float bb = bias ? bias[col] : 0.f;
      #pragma unroll
      for (int r=0;r<4;r++){
        int row = v0 + wm*32 + m*16 + lk*4 + r;
        float val = acc[m][n][r] + bb;
        if (OUT_MODE == 2) val = leaky(val);
        out[(size_t)row*128 + col] = val;
      }
    }
  }
}

// ======== fused pre GEMM: Pd = A@Wd, Ps = A@Ws; Wt combined [128][256] hi/lo ========

__global__ __launch_bounds__(256) void k_pre64(const float* __restrict__ A,
    const unsigned short* __restrict__ Wh, const unsigned short* __restrict__ Wl,
    float* __restrict__ Pd, float* __restrict__ Ps){
  __shared__ unsigned short sAh[64*PAD];
  __shared__ unsigned short sAl[64*PAD];
  int t = threadIdx.x;
  int bid = blockIdx.x;
  int rowt = bid >> 1, colt = bid & 1;
  int v0 = rowt * 64;
  int lane = t & 63, w = t >> 6;
  int wm = w & 1, wn = w >> 1;
  int lr = lane & 15, lk = lane >> 4;
  int brow0 = (colt*64 + wn*32 + lr)*256 + lk*8;
  int brow1 = brow0 + 16*256;
  f32x4 accd[2][2], accs[2][2];
  #pragma unroll
  for (int m=0;m<2;m++)
    #pragma unroll
    for (int n=0;n<2;n++){ accd[m][n] = (f32x4)(0.f); accs[m][n] = (f32x4)(0.f); }

  for (int kb = 0; kb < 128; kb += 64){
    #pragma unroll
    for (int i=0;i<4;i++){
      int u = t + i*256, row = u >> 4, slot = u & 15;
      float4 va = *(const float4*)(A + (size_t)(v0+row)*128 + kb + slot*4);
      unsigned int p0 = split2p(va.x), p1 = split2p(va.y);
      unsigned int p2 = split2p(va.z), p3 = split2p(va.w);
      ushort4v hi, lo;
      hi[0]=(unsigned short)p0; lo[0]=(unsigned short)(p0>>16);
      hi[1]=(unsigned short)p1; lo[1]=(unsigned short)(p1>>16);
      hi[2]=(unsigned short)p2; lo[2]=(unsigned short)(p2>>16);
      hi[3]=(unsigned short)p3; lo[3]=(unsigned short)(p3>>16);
      *(ushort4v*)&sAh[row*PAD + slot*4] = hi;
      *(ushort4v*)&sAl[row*PAD + slot*4] = lo;
    }
    __syncthreads();
    #pragma unroll
    for (int kk=0; kk<64; kk+=32){
      bf16x8 ah[2], al[2], bh[2], bl[2];
      #pragma unroll
      for (int m=0;m<2;m++){
        ah[m] = *(const bf16x8*)&sAh[(wm*32 + m*16 + lr)*PAD + kk + lk*8];
        al[m] = *(const bf16x8*)&sAl[(wm*32 + m*16 + lr)*PAD + kk + lk*8];
      }
      bh[0] = *(const bf16x8*)(Wh + brow0 + kb + kk);
      bh[1] = *(const bf16x8*)(Wh + brow1 + kb + kk);
      bl[0] = *(const bf16x8*)(Wl + brow0 + kb + kk);
      bl[1] = *(const bf16x8*)(Wl + brow1 + kb + kk);
      #pragma unroll
      for (int m=0;m<2;m++)
        #pragma unroll
        for (int n=0;n<2;n++){
          accd[m][n] = __builtin_amdgcn_mfma_f32_16x16x32_bf16(ah[m], bh[n], accd[m][n], 0, 0, 0);
          accd[m][n] = __builtin_amdgcn_mfma_f32_16x16x32_bf16(al[m], bh[n], accd[m][n], 0, 0, 0);
          accd[m][n] = __builtin_amdgcn_mfma_f32_16x16x32_bf16(ah[m], bl[n], accd[m][n], 0, 0, 0);
        }
      bh[0] = *(const bf16x8*)(Wh + brow0 + 128 + kb + kk);
      bh[1] = *(const bf16x8*)(Wh + brow1 + 128 + kb + kk);
      bl[0] = *(const bf16x8*)(Wl + brow0 + 128 + kb + kk);
      bl[1] = *(const bf16x8*)(Wl + brow1 + 128 + kb + kk);
      #pragma unroll
      for (int m=0;m<2;m++)
        #pragma unroll
        for (int n=0;n<2;n++){
          accs[m][n] = __builtin_amdgcn_mfma_f32_16x16x32_bf16(ah[m], bh[n], accs[m][n], 0, 0, 0);
          accs[m][n] = __builtin_amdgcn_mfma_f32_16x16x32_bf16(al[m], bh[n], accs[m][n], 0, 0, 0);
          accs[m][n] = __builtin_amdgcn_mfma_f32_16x16x32_bf16(ah[m], bl[n], accs[m][n], 0, 0, 0);
        }
    }
    __syncthreads();
  }

  #pragma unroll
  for (int m=0;m<2;m++){
    #pragma unroll
    for (int n=0;n<2;n++){
      int col = colt*64 + wn*32 + n*16 + lr;
      #pragma unroll
      for (int r=0;r<4;r++){
        int row = v0 + wm*32 + m*16 + lk*4 + r;
        Pd[(size_t)row*128 + col] = accd[m][n][r];
        Ps[(size_t)row*128 + col] = accs[m][n][r];
      }
    }
  }
}

// ---------------- aggregation (H=128), f32 out, 2 nodes/block, unroll-4 ----------------

__global__ __launch_bounds__(256) void k_agg(const float* __restrict__ Pd, const float* __restrict__ Ps,
                      const float* __restrict__ pre_b, const int* __restrict__ offs,
                      const int* __restrict__ deg, const int* __restrict__ csr,
                      float* __restrict__ aggf){
  int t = threadIdx.x;
  int v = blockIdx.x*2 + (t >> 7);
  int f = t & 127;
  int off = offs[v], d = deg[v];
  float hb = Pd[(size_t)v*128 + f] + pre_b[f];
  float s=0.f, q=0.f, mx=-INFINITY, mn=INFINITY;
  int i = 0;
  for (; i+4 <= d; i += 4){
    int i0 = csr[off+i], i1 = csr[off+i+1], i2 = csr[off+i+2], i3 = csr[off+i+3];
    float h0 = hb + Ps[(size_t)i0*128 + f];
    float h1 = hb + Ps[(size_t)i1*128 + f];
    float h2 = hb + Ps[(size_t)i2*128 + f];
    float h3 = hb + Ps[(size_t)i3*128 + f];
    s += (h0+h1) + (h2+h3);
    q = fmaf(h0,h0, fmaf(h1,h1, fmaf(h2,h2, fmaf(h3,h3, q))));
    mx = fmaxf(fmaxf(fmaxf(mx,h0),fmaxf(h1,h2)),h3);
    mn = fminf(fminf(fminf(mn,h0),fminf(h1,h2)),h3);
  }
  for (; i < d; i++){
    int sv = csr[off+i];
    float h = hb + Ps[(size_t)sv*128 + f];
    s += h; q = fmaf(h,h,q);
    mx = fmaxf(mx, h); mn = fminf(mn, h);
  }
  float degc = fmaxf((float)d, 1.f);
  float mean = s/degc;
  float stdv = sqrtf(fmaxf(q/degc - mean*mean, 0.f) + 1e-5f);
  if (d == 0){ mx = 0.f; mn = 0.f; }
  size_t o = (size_t)v*512;
  aggf[o+f]      = mean;
  aggf[o+128+f]  = stdv;
  aggf[o+256+f]  = mx;
  aggf[o+384+f]  = mn;
}

// ======== fused post+lin GEMM: nxt = (state@W0 + agg@W1 + amp*(agg@W2) + att*(agg@W3) + post_b) @ lin_w + lin_b ========
// grid V/64, block 512 = 8 waves; wave w covers cols w*16.
// Stage 1 = postY (A read once, scaling commuted to epilogue); post tile split hi/lo into LDS (pitch PAD2);
// Stage 2 = lin GEMM from LDS (K=128), B from global(L2).

__global__ __launch_bounds__(512) void k_postlin(const float* __restrict__ state,
    const float* __restrict__ aggf, const float* __restrict__ amp, const float* __restrict__ att,
    const unsigned short* __restrict__ Wh, const unsigned short* __restrict__ Wl,
    const float* __restrict__ post_b,
    const unsigned short* __restrict__ LWh, const unsigned short* __restrict__ LWl,
    const float* __restrict__ lin_b, float* __restrict__ out){
  __shared__ unsigned short sAh[64*PAD2];  // pitch PAD in stage 1, PAD2 in stage 2
  __shared__ unsigned short sAl[64*PAD2];
  __shared__ float sScl[2][64];
  int t = threadIdx.x;
  int v0 = blockIdx.x * 64;
  if (t < 64) sScl[0][t] = amp[v0+t];
  else if (t < 128) sScl[1][t-64] = att[v0+t-64];
  int lane = t & 63, w = t >> 6;     // wave w (0..7): cols w*16 .. w*16+15
  int lr = lane & 15, lk = lane >> 4;
  int bb0 = (w*16 + lr)*1664 + lk*8;
  f32x4 a1[4], a2[4], a3[4];
  #pragma unroll
  for (int m=0;m<4;m++){ a1[m]=(f32x4)(0.f); a2[m]=(f32x4)(0.f); a3[m]=(f32x4)(0.f); }

  // ---- state part: K = 128, W0 region ----
  for (int kb = 0; kb < 128; kb += 64){
    #pragma unroll
    for (int i=0;i<2;i++){
      int u = t + i*512, row = u >> 4, slot = u & 15;
      float4 va = *(const float4*)(state + (size_t)(v0+row)*128 + kb + slot*4);
      unsigned int p0 = split2p(va.x), p1 = split2p(va.y);
      unsigned int p2 = split2p(va.z), p3 = split2p(va.w);
      ushort4v hi, lo;
      hi[0]=(unsigned short)p0; lo[0]=(unsigned short)(p0>>16);
      hi[1]=(unsigned short)p1; lo[1]=(unsigned short)(p1>>16);
      hi[2]=(unsigned short)p2; lo[2]=(unsigned short)(p2>>16);
      hi[3]=(unsigned short)p3; lo[3]=(unsigned short)(p3>>16);
      *(ushort4v*)&sAh[row*PAD + slot*4] = hi;
      *(ushort4v*)&sAl[row*PAD + slot*4] = lo;
    }
    __syncthreads();
    #pragma unroll
    for (int kk=0; kk<64; kk+=32){
      bf16x8 ah[4], al[4], bh, bl;
      #pragma unroll
      for (int m=0;m<4;m++){
        ah[m] = *(const bf16x8*)&sAh[(m*16 + lr)*PAD + kk + lk*8];
        al[m] = *(const bf16x8*)&sAl[(m*16 + lr)*PAD + kk + lk*8];
      }
      bh = *(const bf16x8*)(Wh + bb0 + kb + kk);
      bl = *(const bf16x8*)(Wl + bb0 + kb + kk);
      #pragma unroll
      for (int m=0;m<4;m++){
        a1[m] = __builtin_amdgcn_mfma_f32_16x16x32_bf16(ah[m], bh, a1[m], 0, 0, 0);
        a1[m] = __builtin_amdgcn_mfma_f32_16x16x32_bf16(al[m], bh, a1[m], 0, 0, 0);
        a1[m] = __builtin_amdgcn_mfma_f32_16x16x32_bf16(ah[m], bl, a1[m], 0, 0, 0);
      }
    }
    __syncthreads();
  }

  // ---- agg part: K = 512, W1/W2/W3 regions on the SAME staged A ----
  for (int kb = 0; kb < 512; kb += 64){
    #pragma unroll
    for (int i=0;i<2;i++){
      int u = t + i*512, row = u >> 4, slot = u & 15;
      float4 va = *(const float4*)(aggf + (size_t)(v0+row)*512 + kb + slot*4);
      unsigned int p0 = split2p(va.x), p1 = split2p(va.y);
      unsigned int p2 = split2p(va.z), p3 = split2p(va.w);
      ushort4v hi, lo;
      hi[0]=(unsigned short)p0; lo[0]=(unsigned short)(p0>>16);
      hi[1]=(unsigned short)p1; lo[1]=(unsigned short)(p1>>16);
      hi[2]=(unsigned short)p2; lo[2]=(unsigned short)(p2>>16);
      hi[3]=(unsigned short)p3; lo[3]=(unsigned short)(p3>>16);
      *(ushort4v*)&sAh[row*PAD + slot*4] = hi;
      *(ushort4v*)&sAl[row*PAD + slot*4] = lo;
    }
    __syncthreads();
    #pragma unroll
    for (int kk=0; kk<64; kk+=32){
      bf16x8 ah[4], al[4];
      #pragma unroll
      for (int m=0;m<4;m++){
        ah[m] = *(const bf16x8*)&sAh[(m*16 + lr)*PAD + kk + lk*8];
        al[m] = *(const bf16x8*)&sAl[(m*16 + lr)*PAD + kk + lk*8];
      }
      #pragma unroll
      for (int j=0;j<3;j++){
        int off = 128 + j*512 + kb + kk;
        bf16x8 bh = *(const bf16x8*)(Wh + bb0 + off);
        bf16x8 bl = *(const bf16x8*)(Wl + bb0 + off);
        #pragma unroll
        for (int m=0;m<4;m++){
          f32x4 acc = (j==0) ? a1[m] : (j==1) ? a2[m] : a3[m];
          acc = __builtin_amdgcn_mfma_f32_16x16x32_bf16(ah[m], bh, acc, 0, 0, 0);
          acc = __builtin_amdgcn_mfma_f32_16x16x32_bf16(al[m], bh, acc, 0, 0, 0);
          acc = __builtin_amdgcn_mfma_f32_16x16x32_bf16(ah[m], bl, acc, 0, 0, 0);
          if (j==0) a1[m] = acc; else if (j==1) a2[m] = acc; else a3[m] = acc;
        }
      }
    }
    __syncthreads();
  }

  // ---- post epilogue: post_out = a1 + post_b + amp*a2 + att*a3, split hi/lo into LDS (pitch PAD2) ----
  {
    int col = w*16 + lr;
    float bbv = post_b[col];
    #pragma unroll
    for (int m=0;m<4;m++){
      #pragma unroll
      for (int r=0;r<4;r++){
        int rl = m*16 + lk*4 + r;
        float val = a1[m][r] + bbv + sScl[0][rl]*a2[m][r] + sScl[1][rl]*a3[m][r];
        unsigned int p = split2p(val);
        sAh[rl*PAD2 + col] = (unsigned short)p;
        sAl[rl*PAD2 + col] = (unsigned short)(p >> 16);
      }
    }
  }
  __syncthreads();

  // ---- fused lin stage: out = post_tile @ lin_w + lin_b, K = 128 ----
  {
    int bb1 = (w*16 + lr)*128 + lk*8;
    f32x4 c[4];
    #pragma unroll
    for (int m=0;m<4;m++) c[m] = (f32x4)(0.f);
    #pragma unroll
    for (int kk=0; kk<128; kk+=32){
      bf16x8 ah[4], al[4];
      #pragma unroll
      for (int m=0;m<4;m++){
        ah[m] = *(const bf16x8*)&sAh[(m*16 + lr)*PAD2 + kk + lk*8];
        al[m] = *(const bf16x8*)&sAl[(m*16 + lr)*PAD2 + kk + lk*8];
      }
      bf16x8 bh = *(const bf16x8*)(LWh + bb1 + kk);
      bf16x8 bl = *(const bf16x8*)(LWl + bb1 + kk);
      #pragma unroll
      for (int m=0;m<4;m++){
        c[m] = __builtin_amdgcn_mfma_f32_16x16x32_bf16(ah[m], bh, c[m], 0, 0, 0);
        c[m] = __builtin_amdgcn_mfma_f32_16x16x32_bf16(al[m], bh, c[m], 0, 0, 0);
        c[m] = __builtin_amdgcn_mfma_f32_16x16x32_bf16(ah[m], bl, c[m], 0, 0, 0);
      }
    }
    int col = w*16 + lr;
    float lbv = lin_b[col];
    #pragma unroll
    for (int m=0;m<4;m++){
      #pragma unroll
      for (int r=0;r<4;r++){
        int rl = m*16 + lk*4 + r;
        out[(size_t)(v0+rl)*128 + col] = c[m][r] + lbv;
      }
    }
  }
}

// ---------------- readout tail ----------------

__global__ void k_tail(const float* __restrict__ h1, const float* __restrict__ r2_w,
                       const float* __restrict__ r2_b, const float* __restrict__ r3_w,
                       const float* __restrict__ r3_b, const float* __restrict__ target_n,
                       float* __restrict__ out, float* __restrict__ gacc){
  __shared__ float sh[16][129];
  __shared__ float h2[16][8];
  __shared__ float red[128];
  int t = threadIdx.x; // 128
  int v0 = blockIdx.x * 16;
  for (int r=0;r<16;r++) sh[r][t] = h1[(size_t)(v0+r)*128 + t];
  __syncthreads();
  int n = t >> 3, o = t & 7;
  float acc = r2_b[o];
  for (int k=0;k<128;k++) acc = fmaf(sh[n][k], r2_w[k*8+o], acc);
  h2[n][o] = leaky(acc);
  __syncthreads();
  float err = 0.f;
  if (t < 48){
    int n3 = t / 3, o3 = t % 3;
    float a = r3_b[o3];
    #pragma unroll
    for (int k=0;k<8;k++) a = fmaf(h2[n3][k], r3_w[k*3+o3], a);
    a = leaky(a);
    int v = v0 + n3;
    out[(size_t)v*3 + o3] = a;
    float d = a - target_n[(size_t)v*3 + o3];
    err = d*d;
  }
  red[t] = err; __syncthreads();
  for (int s=64;s>0;s>>=1){ if (t<s) red[t]+=red[t+s]; __syncthreads(); }
  if (t==0) atomicAdd(&gacc[v0 / NN], red[0]);
}

__global__ void k_finalize(const float* __restrict__ gacc, float* __restrict__ out){
  __shared__ float red[128];
  int t = threadIdx.x; // 128
  float a = gacc[t];
  out[(size_t)V*3 + 1 + t] = a / (float)(NN*3);
  red[t] = a; __syncthreads();
  for (int s=64;s>0;s>>=1){ if (t<s) red[t]+=red[t+s]; __syncthreads(); }
  if (t==0) out[(size_t)V*3] = red[0] / (float)(V*3);
}

// ---------------- launch ----------------

extern "C" void kernel_launch(void* const* d_in, const int* in_sizes, int n_in,
                              void* d_out, int out_size, void* d_ws, size_t ws_size,
                              hipStream_t stream){
  const float* x        = (const float*)d_in[0];
  const int*   ei       = (const int*)d_in[1];
  const float* target_n = (const float*)d_in[2];
  const float* pre1_w = (const float*)d_in[4];
  const float* pre1_b = (const float*)d_in[5];
  const float* post1_w= (const float*)d_in[6];
  const float* post1_b= (const float*)d_in[7];
  const float* lin1_w = (const float*)d_in[8];
  const float* lin1_b = (const float*)d_in[9];
  const float* pre_w  = (const float*)d_in[10];
  const float* pre_b  = (const float*)d_in[11];
  const float* post_w = (const float*)d_in[12];
  const float* post_b = (const float*)d_in[13];
  const float* lin_w  = (const float*)d_in[14];
  const float* lin_b  = (const float*)d_in[15];
  const float* r1_w = (const float*)d_in[16];
  const float* r1_b = (const float*)d_in[17];
  const float* r2_w = (const float*)d_in[18];
  const float* r2_b = (const float*)d_in[19];
  const float* r3_w = (const float*)d_in[20];
  const float* r3_b = (const float*)d_in[21];
  float* out = (float*)d_out;

  char* wp = (char*)d_ws;
  auto alloc = [&](size_t bytes){ void* p = (void*)wp; wp += (bytes + 255) & ~(size_t)255; return p; };
  // zero region must stay contiguous: deg, cursor, avg_acc, gacc
  int*   deg     = (int*)  alloc((size_t)V*4);
  int*   cursor  = (int*)  alloc((size_t)V*4);
  float* avg_acc = (float*)alloc(4);
  float* gacc    = (float*)alloc((size_t)NB*4);
  int*   offs    = (int*)  alloc((size_t)(V+1)*4);
  int*   csr     = (int*)  alloc((size_t)E*4);
  float* amp     = (float*)alloc((size_t)V*4);
  float* att     = (float*)alloc((size_t)V*4);
  float* Pd      = (float*)alloc((size_t)V*H*4);
  float* Ps      = (float*)alloc((size_t)V*H*4);
  float* aggf    = (float*)alloc((size_t)V*512*4);     // 64 MB; layer-1 scratch aliases in here
  float* tmpf    = (float*)alloc((size_t)V*H*4);
  float* stA     = (float*)alloc((size_t)V*H*4);
  float* stB     = (float*)alloc((size_t)V*H*4);
  unsigned short* wt_pre_h   = (unsigned short*)alloc((size_t)H*2*H*2);  // [128][256]
  unsigned short* wt_pre_l   = (unsigned short*)alloc((size_t)H*2*H*2);
  unsigned short* wt_lin_h   = (unsigned short*)alloc((size_t)H*H*2);
  unsigned short* wt_lin_l   = (unsigned short*)alloc((size_t)H*H*2);
  unsigned short* wt_lin1_h  = (unsigned short*)alloc((size_t)H*H*2);
  unsigned short* wt_lin1_l  = (unsigned short*)alloc((size_t)H*H*2);
  unsigned short* wt_r1_h    = (unsigned short*)alloc((size_t)H*H*2);
  unsigned short* wt_r1_l    = (unsigned short*)alloc((size_t)H*H*2);
  unsigned short* wt_post_h  = (unsigned short*)alloc((size_t)13*H*H*2);
  unsigned short* wt_post_l  = (unsigned short*)alloc((size_t)13*H*H*2);

  // layer-1 scratch aliased into aggf (used strictly before first k_agg)
  float* agg1 = aggf;                                  // V*8 f32 = 1 MB
  float* in26 = aggf + (size_t)V*8;                    // V*26 f32 = 3.4 MB

  int zeroN = (int)(((char*)offs - (char*)deg) / 4);
  k_zero_i<<<(zeroN+255)/256, 256, 0, stream>>>(deg, zeroN);
  k_deg<<<E/256, 256, 0, stream>>>(ei, deg);
  k_scan<<<1, 1024, 0, stream>>>(deg, offs);
  k_avglog<<<V/256, 256, 0, stream>>>(deg, avg_acc);
  k_ampatt<<<V/256, 256, 0, stream>>>(deg, avg_acc, amp, att);
  k_fill<<<E/256, 256, 0, stream>>>(ei, offs, cursor, csr);

  // weight prep (bf16 hi/lo, transposed)
  {
    dim3 b(32,8);
    k_wt2<<<dim3(8,4),  b, 0, stream>>>(pre_w,   wt_pre_h,  wt_pre_l, 256, 128);  // [256,128] -> [128][256]
    k_wt2<<<dim3(52,4), b, 0, stream>>>(post_w,  wt_post_h, wt_post_l, 1664, 128);
    k_wt2<<<dim3(4,4),  b, 0, stream>>>(lin_w,   wt_lin_h,  wt_lin_l,  128, 128);
    k_wt2<<<dim3(4,4),  b, 0, stream>>>(lin1_w,  wt_lin1_h, wt_lin1_l, 128, 128);
    k_wt2<<<dim3(4,4),  b, 0, stream>>>(r1_w,    wt_r1_h,   wt_r1_l,   128, 128);
  }

  // layer 1 (F=2) — all f32
  k_l1_proj<<<V/256, 256, 0, stream>>>(x, pre1_w, Pd, Ps);
  k_l1_agg<<<V/256, 256, 0, stream>>>(Pd, Ps, pre1_b, offs, deg, csr, agg1);
  k_l1_in26<<<V/256, 256, 0, stream>>>(x, agg1, amp, att, in26);
  k_gemm26<<<V/16, 128, 0, stream>>>(in26, post1_w, post1_b, tmpf);
  k_lin64<0><<<V/64, 256, 0, stream>>>(tmpf, wt_lin1_h, wt_lin1_l, lin1_b, stA);

  // 3 propagation layers (H=128): pre -> agg -> fused post+lin
  float* cur = stA;
  float* nxt = stB;
  for (int l=0; l<3; l++){
    k_pre64<<<(V/64)*2, 256, 0, stream>>>(cur, wt_pre_h, wt_pre_l, Pd, Ps);
    k_agg<<<V/2, 256, 0, stream>>>(Pd, Ps, pre_b, offs, deg, csr, aggf);
    k_postlin<<<V/64, 512, 0, stream>>>(cur, aggf, amp, att, wt_post_h, wt_post_l, post_b,
                                        wt_lin_h, wt_lin_l, lin_b, nxt);
    float* t2 = cur; cur = nxt; nxt = t2;
  }

  // readout
  k_lin64<2><<<V/64, 256, 0, stream>>>(cur, wt_r1_h, wt_r1_l, r1_b, tmpf);
  k_tail<<<V/16, 128, 0, stream>>>(tmpf, r2_w, r2_b, r3_w, r3_b, target_n, out, gacc);
  k_finalize<<<1, 128, 0, stream>>>(gacc, out);
}